// Round 3
// baseline (30834.332 us; speedup 1.0000x reference)
//
#include <hip/hip_runtime.h>

typedef unsigned short ushort_t;

__device__ __forceinline__ float bf2f(ushort_t u) {
  unsigned int i = ((unsigned int)u) << 16;
  return __builtin_bit_cast(float, i);
}
__device__ __forceinline__ ushort_t f2bf(float f) {
  unsigned int x = __builtin_bit_cast(unsigned int, f);
  unsigned int r = (x + 0x7FFFu + ((x >> 16) & 1u)) >> 16;
  return (ushort_t)r;
}

// ---------------- naive GEMM (bisect): C(MxN) = A(MxK) * B(NxK)^T ----------------
// One thread per output element. A: fp32 or bf16 (template). B: fp32 (weights,
// read straight from d_in — no conversion). fp32 accumulate. No LDS, no MFMA.
template <int A_F32, int OUT_BF16>
__global__ __launch_bounds__(256)
void gemm_simple(const void* __restrict__ Av, const float* __restrict__ B,
                 void* __restrict__ Cv, int M, int N, int K) {
  const int c = blockIdx.x * 16 + (threadIdx.x & 15);
  const int r = blockIdx.y * 16 + (threadIdx.x >> 4);
  if (r >= M || c >= N) return;
  const float* Bp = B + (long)c * K;
  float acc = 0.f;
  if (A_F32) {
    const float* Ap = (const float*)Av + (long)r * K;
#pragma unroll 8
    for (int k = 0; k < K; ++k) acc += Ap[k] * Bp[k];
  } else {
    const ushort_t* Ap = (const ushort_t*)Av + (long)r * K;
#pragma unroll 8
    for (int k = 0; k < K; ++k) acc += bf2f(Ap[k]) * Bp[k];
  }
  if (OUT_BF16) ((ushort_t*)Cv)[(long)r * N + c] = f2bf(acc);
  else          ((float*)Cv)[(long)r * N + c] = acc;
}

// ---------------- RMSNorm row kernel: fp32 in -> bf16 out ----------------
__global__ __launch_bounds__(256)
void rmsnorm_kernel(const float* __restrict__ in, const float* __restrict__ w,
                    ushort_t* __restrict__ out, int R) {
  const long row = blockIdx.x;
  const float* x = in + row * R;
  const int tid = threadIdx.x;
  float ss = 0.f;
  for (int i = tid; i < R; i += 256) { float v = x[i]; ss += v * v; }
#pragma unroll
  for (int off = 32; off; off >>= 1) ss += __shfl_xor(ss, off);
  __shared__ float warr[4];
  if ((tid & 63) == 0) warr[tid >> 6] = ss;
  __syncthreads();
  const float tot = warr[0] + warr[1] + warr[2] + warr[3];
  const float rs = rsqrtf(tot / (float)R + 1e-6f);
  for (int i = tid; i < R; i += 256) out[row * R + i] = f2bf(x[i] * rs * w[i]);
}

// ---------------- RoPE (interleaved pairs), bf16 -> bf16 ----------------
// in[row][hh*64 + 2i], row = b*2048+s; cos/sin indexed (s, i), i<32
__global__ __launch_bounds__(256)
void rope_kernel(const ushort_t* __restrict__ in, ushort_t* __restrict__ out,
                 const float* __restrict__ fc, const float* __restrict__ fs, int heads) {
  const int idx = blockIdx.x * 256 + threadIdx.x;
  const int total = 4096 * heads * 32;
  if (idx >= total) return;
  const int i = idx & 31;
  const int rest = idx >> 5;
  const int hh = rest % heads;
  const int row = rest / heads;
  const int srow = row & 2047;
  const float c = fc[srow * 32 + i];
  const float s = fs[srow * 32 + i];
  const long base = (long)row * heads * 64 + hh * 64 + 2 * i;
  const float x0 = bf2f(in[base]);
  const float x1 = bf2f(in[base + 1]);
  out[base] = f2bf(x0 * c - x1 * s);
  out[base + 1] = f2bf(x0 * s + x1 * c);
}

// ---------------- NAIVE causal attention: 1 wave per query row ----------------
__global__ __launch_bounds__(64)
void attn_naive(const ushort_t* __restrict__ qn, const ushort_t* __restrict__ qrs,
                const ushort_t* __restrict__ kn, const ushort_t* __restrict__ kr,
                const ushort_t* __restrict__ v, ushort_t* __restrict__ out) {
  const int lane = threadIdx.x;
  const int bh = blockIdx.y, b = bh >> 4, h = bh & 15;
  const int qrow = blockIdx.x;
  const long grow = (long)b * 2048 + qrow;
  __shared__ float qsm[128];
  const float scale = 0.08838834764831845f;  // 1/sqrt(128)
  qsm[lane] = bf2f(qn[grow * 1024 + h * 64 + lane]) * scale;
  qsm[64 + lane] = bf2f(qrs[grow * 64 + lane]) * scale;
  __syncthreads();

  float m = -1e30f, l = 0.f, a0 = 0.f, a1 = 0.f;
  const int ntiles = qrow / 64 + 1;
  for (int t = 0; t < ntiles; ++t) {
    const int k0 = t * 64;
    const int key = k0 + lane;
    const long krow = (long)b * 2048 + key;
    float s = 0.f;
#pragma unroll 8
    for (int d = 0; d < 64; ++d) s += qsm[d] * bf2f(kn[krow * 1024 + h * 64 + d]);
#pragma unroll 8
    for (int d = 0; d < 64; ++d) s += qsm[64 + d] * bf2f(kr[krow * 1024 + h * 64 + d]);
    const bool valid = key <= qrow;
    s = valid ? s : -1e30f;
    float tm = s;
#pragma unroll
    for (int off = 32; off; off >>= 1) tm = fmaxf(tm, __shfl_xor(tm, off));
    const float mn = fmaxf(m, tm);
    const float f = __expf(m - mn);
    const float p = valid ? __expf(s - mn) : 0.f;
    float ts = p;
#pragma unroll
    for (int off = 32; off; off >>= 1) ts += __shfl_xor(ts, off);
    l = l * f + ts;
    a0 *= f; a1 *= f; m = mn;
    for (int j = 0; j < 64; ++j) {
      const float pj = __shfl(p, j);
      const long vrow = (long)b * 2048 + k0 + j;
      a0 += pj * bf2f(v[vrow * 2048 + h * 128 + lane]);
      a1 += pj * bf2f(v[vrow * 2048 + h * 128 + 64 + lane]);
    }
  }
  const float inv = 1.f / l;
  out[grow * 2048 + h * 128 + lane] = f2bf(a0 * inv);
  out[grow * 2048 + h * 128 + 64 + lane] = f2bf(a1 * inv);
}

// ---------------- launch ----------------
extern "C" void kernel_launch(void* const* d_in, const int* in_sizes, int n_in,
                              void* d_out, int out_size, void* d_ws, size_t ws_size,
                              hipStream_t stream) {
  const float* x      = (const float*)d_in[0];
  const float* fcos   = (const float*)d_in[1];
  const float* fsin   = (const float*)d_in[2];
  const float* w_cq   = (const float*)d_in[3];
  const float* w_dqn  = (const float*)d_in[4];
  const float* w_dqr  = (const float*)d_in[5];
  const float* w_ckv  = (const float*)d_in[6];
  const float* w_dkn  = (const float*)d_in[7];
  const float* w_dv   = (const float*)d_in[8];
  const float* w_kr   = (const float*)d_in[9];
  const float* w_proj = (const float*)d_in[10];
  const float* qnw    = (const float*)d_in[11];
  const float* kvnw   = (const float*)d_in[12];
  float* out = (float*)d_out;

  char* ws = (char*)d_ws;
  size_t off = 0;
  auto A = [&](size_t bytes) -> char* {
    char* p = ws + off;
    off += (bytes + 255) & ~(size_t)255;
    return p;
  };
  // ~102 MB total (reduced from 154 MB; secondary ws-overflow suspect)
  float*    cq_f     = (float*)A(4096ull * 1536 * 4);   // later reused for krope_bf
  float*    ckv_f    = (float*)A(4096ull * 512 * 4);    // later reused for qr_bf
  ushort_t* nq_bf    = (ushort_t*)A(4096ull * 1536 * 2);
  ushort_t* nkv_bf   = (ushort_t*)A(4096ull * 512 * 2);
  ushort_t* qnope_bf = (ushort_t*)A(4096ull * 1024 * 2);
  ushort_t* knope_bf = (ushort_t*)A(4096ull * 1024 * 2);
  ushort_t* v_bf     = (ushort_t*)A(4096ull * 2048 * 2);
  ushort_t* kraw_bf  = (ushort_t*)A(4096ull * 64 * 2);
  ushort_t* qrs_bf   = (ushort_t*)A(4096ull * 64 * 2);
  ushort_t* attn_bf  = (ushort_t*)A(4096ull * 2048 * 2);
  ushort_t* qr_bf    = (ushort_t*)ckv_f;  // ckv_f dead after rmsnorm_kv; qr written after
  ushort_t* krope_bf = (ushort_t*)cq_f;   // cq_f dead after rmsnorm_q; krope written after

  // cq = x @ w_cq^T (fp32 A, fp32 B, fp32 out); rmsnorm -> bf16
  gemm_simple<1, 0><<<dim3(96, 256), 256, 0, stream>>>(x, w_cq, cq_f, 4096, 1536, 2048);
  rmsnorm_kernel<<<4096, 256, 0, stream>>>(cq_f, qnw, nq_bf, 1536);
  // ckv = x @ w_ckv^T ; rmsnorm -> bf16
  gemm_simple<1, 0><<<dim3(32, 256), 256, 0, stream>>>(x, w_ckv, ckv_f, 4096, 512, 2048);
  rmsnorm_kernel<<<4096, 256, 0, stream>>>(ckv_f, kvnw, nkv_bf, 512);
  // projections (bf16 A, fp32 B, bf16 out)
  gemm_simple<0, 1><<<dim3(64, 256), 256, 0, stream>>>(nq_bf, w_dqn, qnope_bf, 4096, 1024, 1536);
  gemm_simple<0, 1><<<dim3(64, 256), 256, 0, stream>>>(nq_bf, w_dqr, qr_bf, 4096, 1024, 1536);
  gemm_simple<0, 1><<<dim3(64, 256), 256, 0, stream>>>(nkv_bf, w_dkn, knope_bf, 4096, 1024, 512);
  gemm_simple<0, 1><<<dim3(128, 256), 256, 0, stream>>>(nkv_bf, w_dv, v_bf, 4096, 2048, 512);
  gemm_simple<1, 1><<<dim3(4, 256), 256, 0, stream>>>(x, w_kr, kraw_bf, 4096, 64, 2048);
  // swapped rope (per reference): k_rope = rope(q_rope) per head; q_rope_shared = rope(k_rope_raw)
  rope_kernel<<<8192, 256, 0, stream>>>(qr_bf, krope_bf, fcos, fsin, 16);
  rope_kernel<<<512, 256, 0, stream>>>(kraw_bf, qrs_bf, fcos, fsin, 1);
  // attention
  attn_naive<<<dim3(2048, 32), 64, 0, stream>>>(qnope_bf, qrs_bf, knope_bf, krope_bf, v_bf, attn_bf);
  // final projection (bf16 A, fp32 B, fp32 out)
  gemm_simple<0, 0><<<dim3(128, 256), 256, 0, stream>>>(attn_bf, w_proj, out, 4096, 2048, 2048);
}

// Round 4
// 4887.588 us; speedup vs baseline: 6.3087x; 6.3087x over previous
//
#include <hip/hip_runtime.h>

typedef __attribute__((ext_vector_type(4))) float f32x4;
typedef __attribute__((ext_vector_type(8))) short short8;
typedef unsigned short ushort_t;

__device__ __forceinline__ float bf2f(ushort_t u) {
  unsigned int i = ((unsigned int)u) << 16;
  return __builtin_bit_cast(float, i);
}
__device__ __forceinline__ ushort_t f2bf(float f) {
  unsigned int x = __builtin_bit_cast(unsigned int, f);
  unsigned int r = (x + 0x7FFFu + ((x >> 16) & 1u)) >> 16;
  return (ushort_t)r;
}

// ---------------- fp32 -> bf16 convert (vectorized) ----------------
__global__ __launch_bounds__(256) void cvt_f32_bf16(const float* __restrict__ in,
                                                    ushort_t* __restrict__ out, long n) {
  long i = ((long)blockIdx.x * 256 + threadIdx.x) * 4;
  if (i >= n) return;
  float4 v = *(const float4*)(in + i);
  ushort4 o;
  o.x = f2bf(v.x); o.y = f2bf(v.y); o.z = f2bf(v.z); o.w = f2bf(v.w);
  *(ushort4*)(out + i) = o;
}

// ---------------- bf16 MFMA GEMM: C(MxN) = A(MxK) * B(NxK)^T ----------------
// 128x128 tile, BK=64, 4 waves (2x2), each wave 64x64 = 4x4 frags of 16x16x32.
// m97 structure, byte-identical to round 1 (the hypothesis test).
template <int OUT_BF16>
__global__ __launch_bounds__(256)
void gemm_bt(const ushort_t* __restrict__ A, const ushort_t* __restrict__ B,
             void* __restrict__ Cv, int M, int N, int K) {
  __shared__ __align__(16) ushort_t As[128 * 64];
  __shared__ __align__(16) ushort_t Bs[128 * 64];
  const int tid = threadIdx.x;
  const int lane = tid & 63;
  const int wid = tid >> 6;
  const int m0 = blockIdx.y * 128;
  const int n0 = blockIdx.x * 128;
  const int wm = (wid >> 1) * 64;
  const int wn = (wid & 1) * 64;

  f32x4 acc[4][4];
#pragma unroll
  for (int m = 0; m < 4; ++m)
#pragma unroll
    for (int n = 0; n < 4; ++n) acc[m][n] = (f32x4){0.f, 0.f, 0.f, 0.f};

  const int ktiles = K >> 6;
  for (int kt = 0; kt < ktiles; ++kt) {
    const int k0 = kt << 6;
    __syncthreads();
#pragma unroll
    for (int i = 0; i < 4; ++i) {
      const int chunk = (i * 4 + wid) * 1024;
      const int o = chunk + lane * 16;
      const int row = o >> 7;
      const int cb = o & 127;
      const ushort_t* src = A + (long)(m0 + row) * K + (k0 + (cb >> 1));
      __builtin_amdgcn_global_load_lds((const __attribute__((address_space(1))) unsigned int*)src,
                                       (__attribute__((address_space(3))) unsigned int*)((char*)As + chunk),
                                       16, 0, 0);
    }
#pragma unroll
    for (int i = 0; i < 4; ++i) {
      const int chunk = (i * 4 + wid) * 1024;
      const int o = chunk + lane * 16;
      const int row = o >> 7;
      const int cb = o & 127;
      int brow = n0 + row;
      if (brow > N - 1) brow = N - 1;
      const ushort_t* src = B + (long)brow * K + (k0 + (cb >> 1));
      __builtin_amdgcn_global_load_lds((const __attribute__((address_space(1))) unsigned int*)src,
                                       (__attribute__((address_space(3))) unsigned int*)((char*)Bs + chunk),
                                       16, 0, 0);
    }
    __syncthreads();
#pragma unroll
    for (int kk = 0; kk < 2; ++kk) {
      const int kb = kk * 32 + ((lane >> 4) << 3);
      short8 a[4], b[4];
#pragma unroll
      for (int m = 0; m < 4; ++m)
        a[m] = *(const short8*)(As + (wm + m * 16 + (lane & 15)) * 64 + kb);
#pragma unroll
      for (int n = 0; n < 4; ++n)
        b[n] = *(const short8*)(Bs + (wn + n * 16 + (lane & 15)) * 64 + kb);
#pragma unroll
      for (int m = 0; m < 4; ++m)
#pragma unroll
        for (int n = 0; n < 4; ++n)
          acc[m][n] = __builtin_amdgcn_mfma_f32_16x16x32_bf16(a[m], b[n], acc[m][n], 0, 0, 0);
    }
  }
  const int rb = m0 + wm + ((lane >> 4) << 2);
  const int cbase = n0 + wn + (lane & 15);
#pragma unroll
  for (int m = 0; m < 4; ++m)
#pragma unroll
    for (int n = 0; n < 4; ++n) {
      const int c = cbase + n * 16;
      if (c < N) {
#pragma unroll
        for (int j = 0; j < 4; ++j) {
          const long r = rb + m * 16 + j;
          if (OUT_BF16)
            ((ushort_t*)Cv)[r * N + c] = f2bf(acc[m][n][j]);
          else
            ((float*)Cv)[r * N + c] = acc[m][n][j];
        }
      }
    }
}

// ---------------- RMSNorm row kernel: bf16 in -> bf16 out ----------------
__global__ __launch_bounds__(256)
void rmsnorm_bf(const ushort_t* __restrict__ in, const float* __restrict__ w,
                ushort_t* __restrict__ out, int R) {
  const long row = blockIdx.x;
  const ushort_t* x = in + row * R;
  const int tid = threadIdx.x;
  float ss = 0.f;
  for (int i = tid; i < R; i += 256) { float v = bf2f(x[i]); ss += v * v; }
#pragma unroll
  for (int off = 32; off; off >>= 1) ss += __shfl_xor(ss, off);
  __shared__ float warr[4];
  if ((tid & 63) == 0) warr[tid >> 6] = ss;
  __syncthreads();
  const float tot = warr[0] + warr[1] + warr[2] + warr[3];
  const float rs = rsqrtf(tot / (float)R + 1e-6f);
  for (int i = tid; i < R; i += 256) out[row * R + i] = f2bf(bf2f(x[i]) * rs * w[i]);
}

// ---------------- RoPE (interleaved pairs), bf16 -> bf16 ----------------
__global__ __launch_bounds__(256)
void rope_kernel(const ushort_t* __restrict__ in, ushort_t* __restrict__ out,
                 const float* __restrict__ fc, const float* __restrict__ fs, int heads) {
  const int idx = blockIdx.x * 256 + threadIdx.x;
  const int total = 4096 * heads * 32;
  if (idx >= total) return;
  const int i = idx & 31;
  const int rest = idx >> 5;
  const int hh = rest % heads;
  const int row = rest / heads;
  const int srow = row & 2047;
  const float c = fc[srow * 32 + i];
  const float s = fs[srow * 32 + i];
  const long base = (long)row * heads * 64 + hh * 64 + 2 * i;
  const float x0 = bf2f(in[base]);
  const float x1 = bf2f(in[base + 1]);
  out[base] = f2bf(x0 * c - x1 * s);
  out[base + 1] = f2bf(x0 * s + x1 * c);
}

// ---------------- NAIVE causal attention: 1 wave per query row ----------------
__global__ __launch_bounds__(64)
void attn_naive(const ushort_t* __restrict__ qn, const ushort_t* __restrict__ qrs,
                const ushort_t* __restrict__ kn, const ushort_t* __restrict__ kr,
                const ushort_t* __restrict__ v, ushort_t* __restrict__ out) {
  const int lane = threadIdx.x;
  const int bh = blockIdx.y, b = bh >> 4, h = bh & 15;
  const int qrow = blockIdx.x;
  const long grow = (long)b * 2048 + qrow;
  __shared__ float qsm[128];
  const float scale = 0.08838834764831845f;  // 1/sqrt(128)
  qsm[lane] = bf2f(qn[grow * 1024 + h * 64 + lane]) * scale;
  qsm[64 + lane] = bf2f(qrs[grow * 64 + lane]) * scale;
  __syncthreads();

  float m = -1e30f, l = 0.f, a0 = 0.f, a1 = 0.f;
  const int ntiles = qrow / 64 + 1;
  for (int t = 0; t < ntiles; ++t) {
    const int k0 = t * 64;
    const int key = k0 + lane;
    const long krow = (long)b * 2048 + key;
    float s = 0.f;
#pragma unroll 8
    for (int d = 0; d < 64; ++d) s += qsm[d] * bf2f(kn[krow * 1024 + h * 64 + d]);
#pragma unroll 8
    for (int d = 0; d < 64; ++d) s += qsm[64 + d] * bf2f(kr[krow * 1024 + h * 64 + d]);
    const bool valid = key <= qrow;
    s = valid ? s : -1e30f;
    float tm = s;
#pragma unroll
    for (int off = 32; off; off >>= 1) tm = fmaxf(tm, __shfl_xor(tm, off));
    const float mn = fmaxf(m, tm);
    const float f = __expf(m - mn);
    const float p = valid ? __expf(s - mn) : 0.f;
    float ts = p;
#pragma unroll
    for (int off = 32; off; off >>= 1) ts += __shfl_xor(ts, off);
    l = l * f + ts;
    a0 *= f; a1 *= f; m = mn;
    for (int j = 0; j < 64; ++j) {
      const float pj = __shfl(p, j);
      const long vrow = (long)b * 2048 + k0 + j;
      a0 += pj * bf2f(v[vrow * 2048 + h * 128 + lane]);
      a1 += pj * bf2f(v[vrow * 2048 + h * 128 + 64 + lane]);
    }
  }
  const float inv = 1.f / l;
  out[grow * 2048 + h * 128 + lane] = f2bf(a0 * inv);
  out[grow * 2048 + h * 128 + 64 + lane] = f2bf(a1 * inv);
}

// ---------------- launch ----------------
// Workspace is packed by lifetime to total EXACTLY 101,711,872 B — the bound
// proven safe by round 3. Regions and lifetimes (step = launch order below):
//   X      @0         16.8MB: x_bf (dead after kraw gemm) -> qr_bf | knope_bf
//   W      @16.8MB    26.2MB: bf16 weights (wkr lives in CKVNQ instead)
//   CQ     @43.0MB    12.6MB: cq_bf (dead after rmsnorm_q) -> krope | kraw | qrs
//   CKVNQ  @55.6MB    16.8MB: ckv_bf(4.2,dead@rms_kv)+wkr | nq_bf(12.6) -> attn_bf(16.8)
//   NKV    @72.4MB     4.2MB: nkv_bf
//   QNOPE  @76.5MB     8.4MB: qnope_bf
//   V      @84.9MB    16.8MB: v_bf   (total 101,711,872)
extern "C" void kernel_launch(void* const* d_in, const int* in_sizes, int n_in,
                              void* d_out, int out_size, void* d_ws, size_t ws_size,
                              hipStream_t stream) {
  const float* x      = (const float*)d_in[0];
  const float* fcos   = (const float*)d_in[1];
  const float* fsin   = (const float*)d_in[2];
  const float* w_cq   = (const float*)d_in[3];
  const float* w_dqn  = (const float*)d_in[4];
  const float* w_dqr  = (const float*)d_in[5];
  const float* w_ckv  = (const float*)d_in[6];
  const float* w_dkn  = (const float*)d_in[7];
  const float* w_dv   = (const float*)d_in[8];
  const float* w_kr   = (const float*)d_in[9];
  const float* w_proj = (const float*)d_in[10];
  const float* qnw    = (const float*)d_in[11];
  const float* kvnw   = (const float*)d_in[12];
  float* out = (float*)d_out;

  char* ws = (char*)d_ws;
  ushort_t* x_bf     = (ushort_t*)(ws + 0);
  ushort_t* wcq_bf   = (ushort_t*)(ws + 16777216);
  ushort_t* wdqn_bf  = (ushort_t*)(ws + 23068672);
  ushort_t* wdqr_bf  = (ushort_t*)(ws + 26214400);
  ushort_t* wckv_bf  = (ushort_t*)(ws + 29360128);
  ushort_t* wdkn_bf  = (ushort_t*)(ws + 31457280);
  ushort_t* wdv_bf   = (ushort_t*)(ws + 32505856);
  ushort_t* wpr_bf   = (ushort_t*)(ws + 34603008);
  ushort_t* cq_bf    = (ushort_t*)(ws + 42991616);  // CQ region
  ushort_t* krope_bf = (ushort_t*)(ws + 42991616);  //   after cq dead
  ushort_t* kraw_bf  = (ushort_t*)(ws + 51380224);  //   after cq dead
  ushort_t* qrs_bf   = (ushort_t*)(ws + 51904512);  //   after cq dead
  ushort_t* ckv_bf   = (ushort_t*)(ws + 55574528);  // CKVNQ region
  ushort_t* wkr_bf   = (ushort_t*)(ws + 55574528);  //   after ckv dead
  ushort_t* nq_bf    = (ushort_t*)(ws + 59768832);  //   CKVNQ + 4.2MB
  ushort_t* attn_bf  = (ushort_t*)(ws + 55574528);  //   after nq/wkr dead
  ushort_t* nkv_bf   = (ushort_t*)(ws + 72351744);
  ushort_t* qnope_bf = (ushort_t*)(ws + 76546048);
  ushort_t* qr_bf    = (ushort_t*)(ws + 0);         // X region, after x_bf dead
  ushort_t* knope_bf = (ushort_t*)(ws + 8388608);   // X region + 8.4MB
  ushort_t* v_bf     = (ushort_t*)(ws + 84934656);

  // 1. converts (x + all weights except wkr)
  cvt_f32_bf16<<<8192, 256, 0, stream>>>(x, x_bf, 8388608);
  cvt_f32_bf16<<<3072, 256, 0, stream>>>(w_cq, wcq_bf, 3145728);
  cvt_f32_bf16<<<1536, 256, 0, stream>>>(w_dqn, wdqn_bf, 1572864);
  cvt_f32_bf16<<<1536, 256, 0, stream>>>(w_dqr, wdqr_bf, 1572864);
  cvt_f32_bf16<<<1024, 256, 0, stream>>>(w_ckv, wckv_bf, 1048576);
  cvt_f32_bf16<<<512, 256, 0, stream>>>(w_dkn, wdkn_bf, 524288);
  cvt_f32_bf16<<<1024, 256, 0, stream>>>(w_dv, wdv_bf, 1048576);
  cvt_f32_bf16<<<4096, 256, 0, stream>>>(w_proj, wpr_bf, 4194304);

  // 2. ckv = x @ w_ckv^T ; rmsnorm   (ckv dead after rmsnorm)
  gemm_bt<1><<<dim3(4, 32), 256, 0, stream>>>(x_bf, wckv_bf, ckv_bf, 4096, 512, 2048);
  rmsnorm_bf<<<4096, 256, 0, stream>>>(ckv_bf, kvnw, nkv_bf, 512);
  // 3. wkr convert into freed ckv slot
  cvt_f32_bf16<<<128, 256, 0, stream>>>(w_kr, wkr_bf, 131072);
  // 4. cq = x @ w_cq^T ; rmsnorm    (cq dead after rmsnorm)
  gemm_bt<1><<<dim3(12, 32), 256, 0, stream>>>(x_bf, wcq_bf, cq_bf, 4096, 1536, 2048);
  rmsnorm_bf<<<4096, 256, 0, stream>>>(cq_bf, qnw, nq_bf, 1536);
  // 5. kraw = x @ w_kr^T            (x_bf dead after this)
  gemm_bt<1><<<dim3(1, 32), 256, 0, stream>>>(x_bf, wkr_bf, kraw_bf, 4096, 64, 2048);
  // 6. q projections                (nq dead after qr)
  gemm_bt<1><<<dim3(8, 32), 256, 0, stream>>>(nq_bf, wdqn_bf, qnope_bf, 4096, 1024, 1536);
  gemm_bt<1><<<dim3(8, 32), 256, 0, stream>>>(nq_bf, wdqr_bf, qr_bf, 4096, 1024, 1536);
  // 7. kv projections               (nkv dead after v)
  gemm_bt<1><<<dim3(8, 32), 256, 0, stream>>>(nkv_bf, wdkn_bf, knope_bf, 4096, 1024, 512);
  gemm_bt<1><<<dim3(16, 32), 256, 0, stream>>>(nkv_bf, wdv_bf, v_bf, 4096, 2048, 512);
  // 8. swapped rope (per reference)
  rope_kernel<<<8192, 256, 0, stream>>>(qr_bf, krope_bf, fcos, fsin, 16);
  rope_kernel<<<512, 256, 0, stream>>>(kraw_bf, qrs_bf, fcos, fsin, 1);
  // 9. attention -> attn_bf (overwrites dead ckv/wkr/nq region; reads live CQ/X/QNOPE/V)
  attn_naive<<<dim3(2048, 32), 64, 0, stream>>>(qnope_bf, qrs_bf, knope_bf, krope_bf, v_bf, attn_bf);
  // 10. final projection (fp32 out)
  gemm_bt<0><<<dim3(16, 32), 256, 0, stream>>>(attn_bf, wpr_bf, out, 4096, 2048, 2048);
}

// Round 5
// 676.887 us; speedup vs baseline: 45.5531x; 7.2207x over previous
//
#include <hip/hip_runtime.h>

typedef __attribute__((ext_vector_type(4))) float f32x4;
typedef __attribute__((ext_vector_type(8))) short short8;
typedef unsigned short ushort_t;

__device__ __forceinline__ float bf2f(ushort_t u) {
  unsigned int i = ((unsigned int)u) << 16;
  return __builtin_bit_cast(float, i);
}
__device__ __forceinline__ ushort_t f2bf(float f) {
  unsigned int x = __builtin_bit_cast(unsigned int, f);
  unsigned int r = (x + 0x7FFFu + ((x >> 16) & 1u)) >> 16;
  return (ushort_t)r;
}

// ---------------- fp32 -> bf16 convert (vectorized) ----------------
__global__ __launch_bounds__(256) void cvt_f32_bf16(const float* __restrict__ in,
                                                    ushort_t* __restrict__ out, long n) {
  long i = ((long)blockIdx.x * 256 + threadIdx.x) * 4;
  if (i >= n) return;
  float4 v = *(const float4*)(in + i);
  ushort4 o;
  o.x = f2bf(v.x); o.y = f2bf(v.y); o.z = f2bf(v.z); o.w = f2bf(v.w);
  *(ushort4*)(out + i) = o;
}

// ---------------- bf16 MFMA GEMM: C(MxN) = A(MxK) * B(NxK)^T ----------------
// 128x128 tile, BK=64, 4 waves (2x2). m97 structure (round-4 verified).
template <int OUT_BF16>
__global__ __launch_bounds__(256)
void gemm_bt(const ushort_t* __restrict__ A, const ushort_t* __restrict__ B,
             void* __restrict__ Cv, int M, int N, int K) {
  __shared__ __align__(16) ushort_t As[128 * 64];
  __shared__ __align__(16) ushort_t Bs[128 * 64];
  const int tid = threadIdx.x;
  const int lane = tid & 63;
  const int wid = tid >> 6;
  const int m0 = blockIdx.y * 128;
  const int n0 = blockIdx.x * 128;
  const int wm = (wid >> 1) * 64;
  const int wn = (wid & 1) * 64;

  f32x4 acc[4][4];
#pragma unroll
  for (int m = 0; m < 4; ++m)
#pragma unroll
    for (int n = 0; n < 4; ++n) acc[m][n] = (f32x4){0.f, 0.f, 0.f, 0.f};

  const int ktiles = K >> 6;
  for (int kt = 0; kt < ktiles; ++kt) {
    const int k0 = kt << 6;
    __syncthreads();
#pragma unroll
    for (int i = 0; i < 4; ++i) {
      const int chunk = (i * 4 + wid) * 1024;
      const int o = chunk + lane * 16;
      const int row = o >> 7;
      const int cb = o & 127;
      const ushort_t* src = A + (long)(m0 + row) * K + (k0 + (cb >> 1));
      __builtin_amdgcn_global_load_lds((const __attribute__((address_space(1))) unsigned int*)src,
                                       (__attribute__((address_space(3))) unsigned int*)((char*)As + chunk),
                                       16, 0, 0);
    }
#pragma unroll
    for (int i = 0; i < 4; ++i) {
      const int chunk = (i * 4 + wid) * 1024;
      const int o = chunk + lane * 16;
      const int row = o >> 7;
      const int cb = o & 127;
      int brow = n0 + row;
      if (brow > N - 1) brow = N - 1;
      const ushort_t* src = B + (long)brow * K + (k0 + (cb >> 1));
      __builtin_amdgcn_global_load_lds((const __attribute__((address_space(1))) unsigned int*)src,
                                       (__attribute__((address_space(3))) unsigned int*)((char*)Bs + chunk),
                                       16, 0, 0);
    }
    __syncthreads();
#pragma unroll
    for (int kk = 0; kk < 2; ++kk) {
      const int kb = kk * 32 + ((lane >> 4) << 3);
      short8 a[4], b[4];
#pragma unroll
      for (int m = 0; m < 4; ++m)
        a[m] = *(const short8*)(As + (wm + m * 16 + (lane & 15)) * 64 + kb);
#pragma unroll
      for (int n = 0; n < 4; ++n)
        b[n] = *(const short8*)(Bs + (wn + n * 16 + (lane & 15)) * 64 + kb);
#pragma unroll
      for (int m = 0; m < 4; ++m)
#pragma unroll
        for (int n = 0; n < 4; ++n)
          acc[m][n] = __builtin_amdgcn_mfma_f32_16x16x32_bf16(a[m], b[n], acc[m][n], 0, 0, 0);
    }
  }
  const int rb = m0 + wm + ((lane >> 4) << 2);
  const int cbase = n0 + wn + (lane & 15);
#pragma unroll
  for (int m = 0; m < 4; ++m)
#pragma unroll
    for (int n = 0; n < 4; ++n) {
      const int c = cbase + n * 16;
      if (c < N) {
#pragma unroll
        for (int j = 0; j < 4; ++j) {
          const long r = rb + m * 16 + j;
          if (OUT_BF16)
            ((ushort_t*)Cv)[r * N + c] = f2bf(acc[m][n][j]);
          else
            ((float*)Cv)[r * N + c] = acc[m][n][j];
        }
      }
    }
}

// ---------------- RMSNorm row kernel: bf16 in -> bf16 out ----------------
__global__ __launch_bounds__(256)
void rmsnorm_bf(const ushort_t* __restrict__ in, const float* __restrict__ w,
                ushort_t* __restrict__ out, int R) {
  const long row = blockIdx.x;
  const ushort_t* x = in + row * R;
  const int tid = threadIdx.x;
  float ss = 0.f;
  for (int i = tid; i < R; i += 256) { float v = bf2f(x[i]); ss += v * v; }
#pragma unroll
  for (int off = 32; off; off >>= 1) ss += __shfl_xor(ss, off);
  __shared__ float warr[4];
  if ((tid & 63) == 0) warr[tid >> 6] = ss;
  __syncthreads();
  const float tot = warr[0] + warr[1] + warr[2] + warr[3];
  const float rs = rsqrtf(tot / (float)R + 1e-6f);
  for (int i = tid; i < R; i += 256) out[row * R + i] = f2bf(bf2f(x[i]) * rs * w[i]);
}

// ---------------- RoPE (interleaved pairs), bf16 -> bf16 ----------------
__global__ __launch_bounds__(256)
void rope_kernel(const ushort_t* __restrict__ in, ushort_t* __restrict__ out,
                 const float* __restrict__ fc, const float* __restrict__ fs, int heads) {
  const int idx = blockIdx.x * 256 + threadIdx.x;
  const int total = 4096 * heads * 32;
  if (idx >= total) return;
  const int i = idx & 31;
  const int rest = idx >> 5;
  const int hh = rest % heads;
  const int row = rest / heads;
  const int srow = row & 2047;
  const float c = fc[srow * 32 + i];
  const float s = fs[srow * 32 + i];
  const long base = (long)row * heads * 64 + hh * 64 + 2 * i;
  const float x0 = bf2f(in[base]);
  const float x1 = bf2f(in[base + 1]);
  out[base] = f2bf(x0 * c - x1 * s);
  out[base + 1] = f2bf(x0 * s + x1 * c);
}

// ---------------- V transpose: v[row][h*128+d] -> vt[bh][d][s] ----------------
// Per block: one (b,h), 64 s-rows x 128 d. XOR-swizzled LDS tile (rows 256B).
__global__ __launch_bounds__(256)
void transpose_v(const ushort_t* __restrict__ v, ushort_t* __restrict__ vt) {
  __shared__ __align__(16) ushort_t Ts[64 * 128];  // 16KB; byte(s,d)=s*256+((2d)^((s&15)<<4))
  const int t = threadIdx.x;
  const int bh = blockIdx.y;
  const int b = bh >> 4, h = bh & 15;
  const int s0 = blockIdx.x * 64;
#pragma unroll
  for (int i = 0; i < 4; ++i) {
    const int c = t + 256 * i;
    const int si = c >> 4;
    const int xb = (c & 15) * 16;
    const long src = ((long)b * 2048 + s0 + si) * 2048 + h * 128 + (xb >> 1);
    short8 val = *(const short8*)(v + src);
    *(short8*)((char*)Ts + si * 256 + (xb ^ ((si & 15) << 4))) = val;
  }
  __syncthreads();
  // gather: lanes span 64 consecutive d -> conflict-free (bank = f(d) covers all 32)
  const int d = (t & 63) + ((t >> 7) << 6);
  const int scb = ((t >> 6) & 1) * 4;
#pragma unroll
  for (int i = 0; i < 4; ++i) {
    const int sc = scb + i;
    short8 val;
#pragma unroll
    for (int j = 0; j < 8; ++j) {
      const int s = sc * 8 + j;
      val[j] = (short)*(const ushort_t*)((const char*)Ts + s * 256 + ((2 * d) ^ ((s & 15) << 4)));
    }
    *(short8*)(vt + ((long)bh * 128 + d) * 2048 + s0 + sc * 8) = val;
  }
}

// ---------------- MFMA flash attention ----------------
// Block = 4 waves x 16 q-rows (64-row Q-tile) for one (b,h); K-tiles of 64.
// Q[d<64]=qn[row][h*64+d], Q[d>=64]=qrs[row][d-64]; K likewise (kn, kr per head).
// V via pre-transposed vt[bh][d][s]. All LDS tiles XOR-swizzled (T2, both-sides).
__global__ __launch_bounds__(256)
void attn_mfma(const ushort_t* __restrict__ qn, const ushort_t* __restrict__ qrs,
               const ushort_t* __restrict__ kn, const ushort_t* __restrict__ kr,
               const ushort_t* __restrict__ vt, ushort_t* __restrict__ out) {
  __shared__ __align__(16) ushort_t Ks[8192];   // [64 k][128 d], rows 256B, swizzled
  __shared__ __align__(16) ushort_t Vts[8192];  // [128 d][64 s], rows 128B, swizzled
  __shared__ __align__(16) ushort_t Ps[4096];   // per-wave [16 q][64 k], rows 128B, swizzled
  const int tid = threadIdx.x, lane = tid & 63, wid = tid >> 6;
  const int g = lane >> 4, lq = lane & 15;
  const int bh = blockIdx.y, b = bh >> 4, h = bh & 15;
  const int qt = blockIdx.x;
  const int q0 = qt * 64;
  const int qw0 = q0 + wid * 16;
  const float scale = 0.08838834764831845f;  // 1/sqrt(128)

  // Q A-frags: row = qw0+lq, k-elems d = ks*32 + g*8 .. +7 (gemm_bt-verified map)
  short8 aq[4];
  {
    const long grow = (long)b * 2048 + qw0 + lq;
#pragma unroll
    for (int ks = 0; ks < 4; ++ks) {
      const int d = ks * 32 + g * 8;
      const ushort_t* src = (d < 64) ? (qn + grow * 1024 + h * 64 + d)
                                     : (qrs + grow * 64 + (d - 64));
      aq[ks] = *(const short8*)src;
    }
  }

  f32x4 oacc[8];
#pragma unroll
  for (int n = 0; n < 8; ++n) oacc[n] = (f32x4){0.f, 0.f, 0.f, 0.f};
  float sm[4] = {-3e38f, -3e38f, -3e38f, -3e38f};
  float sl[4] = {0.f, 0.f, 0.f, 0.f};
  char* Pbase = (char*)Ps + wid * 2048;

  for (int kt = 0; kt <= qt; ++kt) {
    const int k0 = kt * 64;
    __syncthreads();  // previous tile fully consumed
    // stage K [64][128] (mixed kn/kr per-lane src, pre-swizzled source)
#pragma unroll
    for (int i = 0; i < 4; ++i) {
      const int cc = wid * 4 + i;
      const int o = cc * 1024 + lane * 16;
      const int row = o >> 8, x = o & 255;
      const int xs = x ^ ((row & 7) << 4);
      const int d = xs >> 1;
      const long krow = (long)b * 2048 + k0 + row;
      const ushort_t* src = (d < 64) ? (kn + krow * 1024 + h * 64 + d)
                                     : (kr + krow * 1024 + h * 64 + (d - 64));
      __builtin_amdgcn_global_load_lds((const __attribute__((address_space(1))) unsigned int*)src,
          (__attribute__((address_space(3))) unsigned int*)((char*)Ks + cc * 1024), 16, 0, 0);
    }
    // stage Vt [128][64]
#pragma unroll
    for (int i = 0; i < 4; ++i) {
      const int cc = wid * 4 + i;
      const int o = cc * 1024 + lane * 16;
      const int dr = o >> 7, x = o & 127;
      const int xs = x ^ ((dr & 7) << 4);
      const int se = xs >> 1;
      const ushort_t* src = vt + ((long)bh * 128 + dr) * 2048 + k0 + se;
      __builtin_amdgcn_global_load_lds((const __attribute__((address_space(1))) unsigned int*)src,
          (__attribute__((address_space(3))) unsigned int*)((char*)Vts + cc * 1024), 16, 0, 0);
    }
    __syncthreads();  // drains vmcnt(0): LDS valid

    // ---- QK^T: S[16q][64k] ----
    f32x4 sacc[4];
#pragma unroll
    for (int n = 0; n < 4; ++n) sacc[n] = (f32x4){0.f, 0.f, 0.f, 0.f};
#pragma unroll
    for (int ks = 0; ks < 4; ++ks) {
      const int x = ks * 64 + g * 16;
#pragma unroll
      for (int n = 0; n < 4; ++n) {
        const int kl = n * 16 + lq;
        short8 bk = *(const short8*)((const char*)Ks + kl * 256 + (x ^ ((kl & 7) << 4)));
        sacc[n] = __builtin_amdgcn_mfma_f32_16x16x32_bf16(aq[ks], bk, sacc[n], 0, 0, 0);
      }
    }
#pragma unroll
    for (int n = 0; n < 4; ++n)
#pragma unroll
      for (int j = 0; j < 4; ++j) sacc[n][j] *= scale;
    if (kt == qt) {  // diagonal tile: causal mask
#pragma unroll
      for (int n = 0; n < 4; ++n) {
        const int key = k0 + n * 16 + lq;
#pragma unroll
        for (int j = 0; j < 4; ++j) {
          const int qrow = q0 + wid * 16 + g * 4 + j;
          if (key > qrow) sacc[n][j] = -3e38f;
        }
      }
    }
    // ---- online softmax (rows j, 16-lane group reduce) ----
    float tmax[4];
#pragma unroll
    for (int j = 0; j < 4; ++j)
      tmax[j] = fmaxf(fmaxf(sacc[0][j], sacc[1][j]), fmaxf(sacc[2][j], sacc[3][j]));
#pragma unroll
    for (int off = 1; off < 16; off <<= 1)
#pragma unroll
      for (int j = 0; j < 4; ++j) tmax[j] = fmaxf(tmax[j], __shfl_xor(tmax[j], off));
    float mn[4], fr[4];
#pragma unroll
    for (int j = 0; j < 4; ++j) {
      mn[j] = fmaxf(sm[j], tmax[j]);
      fr[j] = __expf(sm[j] - mn[j]);
      sm[j] = mn[j];
    }
    f32x4 p[4];
#pragma unroll
    for (int n = 0; n < 4; ++n)
#pragma unroll
      for (int j = 0; j < 4; ++j) p[n][j] = __expf(sacc[n][j] - mn[j]);
    float psum[4];
#pragma unroll
    for (int j = 0; j < 4; ++j) psum[j] = p[0][j] + p[1][j] + p[2][j] + p[3][j];
#pragma unroll
    for (int off = 1; off < 16; off <<= 1)
#pragma unroll
      for (int j = 0; j < 4; ++j) psum[j] += __shfl_xor(psum[j], off);
#pragma unroll
    for (int j = 0; j < 4; ++j) sl[j] = sl[j] * fr[j] + psum[j];
#pragma unroll
    for (int n = 0; n < 8; ++n)
#pragma unroll
      for (int j = 0; j < 4; ++j) oacc[n][j] *= fr[j];
    // ---- P -> LDS (bf16, swizzled; per-wave region, intra-wave in-order LDS) ----
#pragma unroll
    for (int n = 0; n < 4; ++n) {
      const int col2 = (n * 16 + lq) * 2;
#pragma unroll
      for (int j = 0; j < 4; ++j) {
        const int row = g * 4 + j;
        *(ushort_t*)(Pbase + row * 128 + (col2 ^ ((row & 7) << 4))) = f2bf(p[n][j]);
      }
    }
    // ---- PV: O[16q][128d] += P[16q][64k] * Vt[128d][64k]^T ----
#pragma unroll
    for (int ks2 = 0; ks2 < 2; ++ks2) {
      const int x = ks2 * 64 + g * 16;
      short8 pa = *(const short8*)(Pbase + lq * 128 + (x ^ ((lq & 7) << 4)));
#pragma unroll
      for (int nd = 0; nd < 8; ++nd) {
        const int dl = nd * 16 + lq;
        short8 vb = *(const short8*)((const char*)Vts + dl * 128 + (x ^ ((dl & 7) << 4)));
        oacc[nd] = __builtin_amdgcn_mfma_f32_16x16x32_bf16(pa, vb, oacc[nd], 0, 0, 0);
      }
    }
  }
  // ---- epilogue ----
  float inv[4];
#pragma unroll
  for (int j = 0; j < 4; ++j) inv[j] = 1.f / sl[j];
#pragma unroll
  for (int nd = 0; nd < 8; ++nd) {
    const int d = nd * 16 + lq;
#pragma unroll
    for (int j = 0; j < 4; ++j) {
      const long row = (long)b * 2048 + q0 + wid * 16 + g * 4 + j;
      out[row * 2048 + h * 128 + d] = f2bf(oacc[nd][j] * inv[j]);
    }
  }
}

// ---------------- launch ----------------
// Workspace: EXACTLY 101,711,872 B (round-3-proven bound). vt (16.8MB) lives in
// the dead small-weight region [16.8MB, 33.5MB) — wcq..wdv all dead by then;
// wpr (34.6MB) untouched.
extern "C" void kernel_launch(void* const* d_in, const int* in_sizes, int n_in,
                              void* d_out, int out_size, void* d_ws, size_t ws_size,
                              hipStream_t stream) {
  const float* x      = (const float*)d_in[0];
  const float* fcos   = (const float*)d_in[1];
  const float* fsin   = (const float*)d_in[2];
  const float* w_cq   = (const float*)d_in[3];
  const float* w_dqn  = (const float*)d_in[4];
  const float* w_dqr  = (const float*)d_in[5];
  const float* w_ckv  = (const float*)d_in[6];
  const float* w_dkn  = (const float*)d_in[7];
  const float* w_dv   = (const float*)d_in[8];
  const float* w_kr   = (const float*)d_in[9];
  const float* w_proj = (const float*)d_in[10];
  const float* qnw    = (const float*)d_in[11];
  const float* kvnw   = (const float*)d_in[12];
  float* out = (float*)d_out;

  char* ws = (char*)d_ws;
  ushort_t* x_bf     = (ushort_t*)(ws + 0);
  ushort_t* wcq_bf   = (ushort_t*)(ws + 16777216);
  ushort_t* wdqn_bf  = (ushort_t*)(ws + 23068672);
  ushort_t* wdqr_bf  = (ushort_t*)(ws + 26214400);
  ushort_t* wckv_bf  = (ushort_t*)(ws + 29360128);
  ushort_t* wdkn_bf  = (ushort_t*)(ws + 31457280);
  ushort_t* wdv_bf   = (ushort_t*)(ws + 32505856);
  ushort_t* wpr_bf   = (ushort_t*)(ws + 34603008);
  ushort_t* cq_bf    = (ushort_t*)(ws + 42991616);  // CQ region
  ushort_t* krope_bf = (ushort_t*)(ws + 42991616);  //   after cq dead
  ushort_t* kraw_bf  = (ushort_t*)(ws + 51380224);  //   after cq dead
  ushort_t* qrs_bf   = (ushort_t*)(ws + 51904512);  //   after cq dead
  ushort_t* ckv_bf   = (ushort_t*)(ws + 55574528);  // CKVNQ region
  ushort_t* wkr_bf   = (ushort_t*)(ws + 55574528);  //   after ckv dead
  ushort_t* nq_bf    = (ushort_t*)(ws + 59768832);  //   CKVNQ + 4.2MB
  ushort_t* attn_bf  = (ushort_t*)(ws + 55574528);  //   after nq/wkr dead
  ushort_t* nkv_bf   = (ushort_t*)(ws + 72351744);
  ushort_t* qnope_bf = (ushort_t*)(ws + 76546048);
  ushort_t* qr_bf    = (ushort_t*)(ws + 0);         // X region, after x_bf dead
  ushort_t* knope_bf = (ushort_t*)(ws + 8388608);   // X region + 8.4MB
  ushort_t* v_bf     = (ushort_t*)(ws + 84934656);
  ushort_t* vt_bf    = (ushort_t*)(ws + 16777216);  // dead weight region (16.8MB)

  // 1. converts
  cvt_f32_bf16<<<8192, 256, 0, stream>>>(x, x_bf, 8388608);
  cvt_f32_bf16<<<3072, 256, 0, stream>>>(w_cq, wcq_bf, 3145728);
  cvt_f32_bf16<<<1536, 256, 0, stream>>>(w_dqn, wdqn_bf, 1572864);
  cvt_f32_bf16<<<1536, 256, 0, stream>>>(w_dqr, wdqr_bf, 1572864);
  cvt_f32_bf16<<<1024, 256, 0, stream>>>(w_ckv, wckv_bf, 1048576);
  cvt_f32_bf16<<<512, 256, 0, stream>>>(w_dkn, wdkn_bf, 524288);
  cvt_f32_bf16<<<1024, 256, 0, stream>>>(w_dv, wdv_bf, 1048576);
  cvt_f32_bf16<<<4096, 256, 0, stream>>>(w_proj, wpr_bf, 4194304);

  // 2. ckv = x @ w_ckv^T ; rmsnorm
  gemm_bt<1><<<dim3(4, 32), 256, 0, stream>>>(x_bf, wckv_bf, ckv_bf, 4096, 512, 2048);
  rmsnorm_bf<<<4096, 256, 0, stream>>>(ckv_bf, kvnw, nkv_bf, 512);
  // 3. wkr convert into freed ckv slot
  cvt_f32_bf16<<<128, 256, 0, stream>>>(w_kr, wkr_bf, 131072);
  // 4. cq = x @ w_cq^T ; rmsnorm
  gemm_bt<1><<<dim3(12, 32), 256, 0, stream>>>(x_bf, wcq_bf, cq_bf, 4096, 1536, 2048);
  rmsnorm_bf<<<4096, 256, 0, stream>>>(cq_bf, qnw, nq_bf, 1536);
  // 5. kraw = x @ w_kr^T  (x_bf dead after)
  gemm_bt<1><<<dim3(1, 32), 256, 0, stream>>>(x_bf, wkr_bf, kraw_bf, 4096, 64, 2048);
  // 6. q projections  (nq dead after)
  gemm_bt<1><<<dim3(8, 32), 256, 0, stream>>>(nq_bf, wdqn_bf, qnope_bf, 4096, 1024, 1536);
  gemm_bt<1><<<dim3(8, 32), 256, 0, stream>>>(nq_bf, wdqr_bf, qr_bf, 4096, 1024, 1536);
  // 7. kv projections  (nkv dead after; weights dead after)
  gemm_bt<1><<<dim3(8, 32), 256, 0, stream>>>(nkv_bf, wdkn_bf, knope_bf, 4096, 1024, 512);
  gemm_bt<1><<<dim3(16, 32), 256, 0, stream>>>(nkv_bf, wdv_bf, v_bf, 4096, 2048, 512);
  // 8. V transpose into dead weight region
  transpose_v<<<dim3(32, 32), 256, 0, stream>>>(v_bf, vt_bf);
  // 9. swapped rope (per reference)
  rope_kernel<<<8192, 256, 0, stream>>>(qr_bf, krope_bf, fcos, fsin, 16);
  rope_kernel<<<512, 256, 0, stream>>>(kraw_bf, qrs_bf, fcos, fsin, 1);
  // 10. MFMA flash attention
  attn_mfma<<<dim3(32, 32), 256, 0, stream>>>(qnope_bf, qrs_bf, knope_bf, krope_bf, vt_bf, attn_bf);
  // 11. final projection (fp32 out)
  gemm_bt<0><<<dim3(16, 32), 256, 0, stream>>>(attn_bf, wpr_bf, out, 4096, 2048, 2048);
}

// Round 6
// 461.325 us; speedup vs baseline: 66.8386x; 1.4673x over previous
//
#include <hip/hip_runtime.h>

typedef __attribute__((ext_vector_type(4))) float f32x4;
typedef __attribute__((ext_vector_type(8))) short short8;
typedef unsigned short ushort_t;

__device__ __forceinline__ float bf2f(ushort_t u) {
  unsigned int i = ((unsigned int)u) << 16;
  return __builtin_bit_cast(float, i);
}
__device__ __forceinline__ ushort_t f2bf(float f) {
  unsigned int x = __builtin_bit_cast(unsigned int, f);
  unsigned int r = (x + 0x7FFFu + ((x >> 16) & 1u)) >> 16;
  return (ushort_t)r;
}

// ---------------- fp32 -> bf16 convert (vectorized) ----------------
__global__ __launch_bounds__(256) void cvt_f32_bf16(const float* __restrict__ in,
                                                    ushort_t* __restrict__ out, long n) {
  long i = ((long)blockIdx.x * 256 + threadIdx.x) * 4;
  if (i >= n) return;
  float4 v = *(const float4*)(in + i);
  ushort4 o;
  o.x = f2bf(v.x); o.y = f2bf(v.y); o.z = f2bf(v.z); o.w = f2bf(v.w);
  *(ushort4*)(out + i) = o;
}

// ---------------- bf16 MFMA GEMM: C(MxN) = A(MxK) * B(NxK)^T ----------------
// 128x128 tile, BK=64, 4 waves (2x2). m97 structure (round-4 verified).
template <int OUT_BF16>
__global__ __launch_bounds__(256)
void gemm_bt(const ushort_t* __restrict__ A, const ushort_t* __restrict__ B,
             void* __restrict__ Cv, int M, int N, int K) {
  __shared__ __align__(16) ushort_t As[128 * 64];
  __shared__ __align__(16) ushort_t Bs[128 * 64];
  const int tid = threadIdx.x;
  const int lane = tid & 63;
  const int wid = tid >> 6;
  const int m0 = blockIdx.y * 128;
  const int n0 = blockIdx.x * 128;
  const int wm = (wid >> 1) * 64;
  const int wn = (wid & 1) * 64;

  f32x4 acc[4][4];
#pragma unroll
  for (int m = 0; m < 4; ++m)
#pragma unroll
    for (int n = 0; n < 4; ++n) acc[m][n] = (f32x4){0.f, 0.f, 0.f, 0.f};

  const int ktiles = K >> 6;
  for (int kt = 0; kt < ktiles; ++kt) {
    const int k0 = kt << 6;
    __syncthreads();
#pragma unroll
    for (int i = 0; i < 4; ++i) {
      const int chunk = (i * 4 + wid) * 1024;
      const int o = chunk + lane * 16;
      const int row = o >> 7;
      const int cb = o & 127;
      const ushort_t* src = A + (long)(m0 + row) * K + (k0 + (cb >> 1));
      __builtin_amdgcn_global_load_lds((const __attribute__((address_space(1))) unsigned int*)src,
                                       (__attribute__((address_space(3))) unsigned int*)((char*)As + chunk),
                                       16, 0, 0);
    }
#pragma unroll
    for (int i = 0; i < 4; ++i) {
      const int chunk = (i * 4 + wid) * 1024;
      const int o = chunk + lane * 16;
      const int row = o >> 7;
      const int cb = o & 127;
      int brow = n0 + row;
      if (brow > N - 1) brow = N - 1;
      const ushort_t* src = B + (long)brow * K + (k0 + (cb >> 1));
      __builtin_amdgcn_global_load_lds((const __attribute__((address_space(1))) unsigned int*)src,
                                       (__attribute__((address_space(3))) unsigned int*)((char*)Bs + chunk),
                                       16, 0, 0);
    }
    __syncthreads();
#pragma unroll
    for (int kk = 0; kk < 2; ++kk) {
      const int kb = kk * 32 + ((lane >> 4) << 3);
      short8 a[4], b[4];
#pragma unroll
      for (int m = 0; m < 4; ++m)
        a[m] = *(const short8*)(As + (wm + m * 16 + (lane & 15)) * 64 + kb);
#pragma unroll
      for (int n = 0; n < 4; ++n)
        b[n] = *(const short8*)(Bs + (wn + n * 16 + (lane & 15)) * 64 + kb);
#pragma unroll
      for (int m = 0; m < 4; ++m)
#pragma unroll
        for (int n = 0; n < 4; ++n)
          acc[m][n] = __builtin_amdgcn_mfma_f32_16x16x32_bf16(a[m], b[n], acc[m][n], 0, 0, 0);
    }
  }
  const int rb = m0 + wm + ((lane >> 4) << 2);
  const int cbase = n0 + wn + (lane & 15);
#pragma unroll
  for (int m = 0; m < 4; ++m)
#pragma unroll
    for (int n = 0; n < 4; ++n) {
      const int c = cbase + n * 16;
      if (c < N) {
#pragma unroll
        for (int j = 0; j < 4; ++j) {
          const long r = rb + m * 16 + j;
          if (OUT_BF16)
            ((ushort_t*)Cv)[r * N + c] = f2bf(acc[m][n][j]);
          else
            ((float*)Cv)[r * N + c] = acc[m][n][j];
        }
      }
    }
}

// ---------------- RMSNorm row kernel: bf16 in -> bf16 out ----------------
__global__ __launch_bounds__(256)
void rmsnorm_bf(const ushort_t* __restrict__ in, const float* __restrict__ w,
                ushort_t* __restrict__ out, int R) {
  const long row = blockIdx.x;
  const ushort_t* x = in + row * R;
  const int tid = threadIdx.x;
  float ss = 0.f;
  for (int i = tid; i < R; i += 256) { float v = bf2f(x[i]); ss += v * v; }
#pragma unroll
  for (int off = 32; off; off >>= 1) ss += __shfl_xor(ss, off);
  __shared__ float warr[4];
  if ((tid & 63) == 0) warr[tid >> 6] = ss;
  __syncthreads();
  const float tot = warr[0] + warr[1] + warr[2] + warr[3];
  const float rs = rsqrtf(tot / (float)R + 1e-6f);
  for (int i = tid; i < R; i += 256) out[row * R + i] = f2bf(bf2f(x[i]) * rs * w[i]);
}

// ---------------- RoPE (interleaved pairs), bf16 -> bf16 ----------------
__global__ __launch_bounds__(256)
void rope_kernel(const ushort_t* __restrict__ in, ushort_t* __restrict__ out,
                 const float* __restrict__ fc, const float* __restrict__ fs, int heads) {
  const int idx = blockIdx.x * 256 + threadIdx.x;
  const int total = 4096 * heads * 32;
  if (idx >= total) return;
  const int i = idx & 31;
  const int rest = idx >> 5;
  const int hh = rest % heads;
  const int row = rest / heads;
  const int srow = row & 2047;
  const float c = fc[srow * 32 + i];
  const float s = fs[srow * 32 + i];
  const long base = (long)row * heads * 64 + hh * 64 + 2 * i;
  const float x0 = bf2f(in[base]);
  const float x1 = bf2f(in[base + 1]);
  out[base] = f2bf(x0 * c - x1 * s);
  out[base + 1] = f2bf(x0 * s + x1 * c);
}

// ---------------- V transpose: v[row][h*128+d] -> vt[bh][d][s] ----------------
__global__ __launch_bounds__(256)
void transpose_v(const ushort_t* __restrict__ v, ushort_t* __restrict__ vt) {
  __shared__ __align__(16) ushort_t Ts[64 * 128];  // byte(s,d)=s*256+((2d)^((s&15)<<4))
  const int t = threadIdx.x;
  const int bh = blockIdx.y;
  const int b = bh >> 4, h = bh & 15;
  const int s0 = blockIdx.x * 64;
#pragma unroll
  for (int i = 0; i < 4; ++i) {
    const int c = t + 256 * i;
    const int si = c >> 4;
    const int xb = (c & 15) * 16;
    const long src = ((long)b * 2048 + s0 + si) * 2048 + h * 128 + (xb >> 1);
    short8 val = *(const short8*)(v + src);
    *(short8*)((char*)Ts + si * 256 + (xb ^ ((si & 15) << 4))) = val;
  }
  __syncthreads();
  const int d = (t & 63) + ((t >> 7) << 6);
  const int scb = ((t >> 6) & 1) * 4;
#pragma unroll
  for (int i = 0; i < 4; ++i) {
    const int sc = scb + i;
    short8 val;
#pragma unroll
    for (int j = 0; j < 8; ++j) {
      const int s = sc * 8 + j;
      val[j] = (short)*(const ushort_t*)((const char*)Ts + s * 256 + ((2 * d) ^ ((s & 15) << 4)));
    }
    *(short8*)(vt + ((long)bh * 128 + d) * 2048 + s0 + sc * 8) = val;
  }
}

// ---------------- MFMA flash attention v2 ----------------
// Balanced: block `pair` handles q-tiles {pair, 31-pair} -> 33 K-tile-steps each.
// Double-buffered K/Vt staging with counted vmcnt(8) (T3-minimum 2-phase).
// LDS: K 2x16KB + Vt 2x16KB + P 8KB = 72KB -> 2 blocks/CU.
__global__ __launch_bounds__(256)
void attn_mfma(const ushort_t* __restrict__ qn, const ushort_t* __restrict__ qrs,
               const ushort_t* __restrict__ kn, const ushort_t* __restrict__ kr,
               const ushort_t* __restrict__ vt, ushort_t* __restrict__ out) {
  __shared__ __align__(16) ushort_t Ks[2][8192];   // [64 k][128 d], rows 256B, swizzled
  __shared__ __align__(16) ushort_t Vts[2][8192];  // [128 d][64 s], rows 128B, swizzled
  __shared__ __align__(16) ushort_t Ps[4096];      // per-wave [16 q][64 k], swizzled
  const int tid = threadIdx.x, lane = tid & 63, wid = tid >> 6;
  const int g = lane >> 4, lq = lane & 15;
  const int bh = blockIdx.y, b = bh >> 4, h = bh & 15;
  const float scale = 0.08838834764831845f;  // 1/sqrt(128)
  char* Pbase = (char*)Ps + wid * 2048;

  // stage K-tile kt into buffer bsel: 8 global_load_lds per wave (4 K + 4 Vt)
  auto stage = [&](int bsel, int kt) {
    const int k0s = kt * 64;
#pragma unroll
    for (int i = 0; i < 4; ++i) {
      const int cc = wid * 4 + i;
      const int o = cc * 1024 + lane * 16;
      {
        const int row = o >> 8;
        const int dK = ((o & 255) ^ ((row & 7) << 4)) >> 1;
        const long krow = (long)b * 2048 + k0s + row;
        const ushort_t* srcK = (dK < 64) ? (kn + krow * 1024 + h * 64 + dK)
                                         : (kr + krow * 1024 + h * 64 + (dK - 64));
        __builtin_amdgcn_global_load_lds((const __attribute__((address_space(1))) unsigned int*)srcK,
            (__attribute__((address_space(3))) unsigned int*)((char*)Ks[bsel] + cc * 1024), 16, 0, 0);
      }
      {
        const int dr = o >> 7;
        const int se = ((o & 127) ^ ((dr & 7) << 4)) >> 1;
        const ushort_t* srcV = vt + ((long)bh * 128 + dr) * 2048 + k0s + se;
        __builtin_amdgcn_global_load_lds((const __attribute__((address_space(1))) unsigned int*)srcV,
            (__attribute__((address_space(3))) unsigned int*)((char*)Vts[bsel] + cc * 1024), 16, 0, 0);
      }
    }
  };

  const int pair = blockIdx.x;
  for (int half = 0; half < 2; ++half) {
    const int qt = half ? (31 - pair) : pair;
    const int q0 = qt * 64;
    // Q A-frags: row = q0 + wid*16 + lq, k-elems d = ks*32 + g*8 .. +7
    short8 aq[4];
    {
      const long grow = (long)b * 2048 + q0 + wid * 16 + lq;
#pragma unroll
      for (int ks = 0; ks < 4; ++ks) {
        const int d = ks * 32 + g * 8;
        const ushort_t* src = (d < 64) ? (qn + grow * 1024 + h * 64 + d)
                                       : (qrs + grow * 64 + (d - 64));
        aq[ks] = *(const short8*)src;
      }
    }
    f32x4 oacc[8];
#pragma unroll
    for (int n = 0; n < 8; ++n) oacc[n] = (f32x4){0.f, 0.f, 0.f, 0.f};
    float sm[4] = {-3e38f, -3e38f, -3e38f, -3e38f};
    float sl[4] = {0.f, 0.f, 0.f, 0.f};

    int cur = 0;
    stage(0, 0);
    for (int kt = 0; kt <= qt; ++kt) {
      const int k0 = kt * 64;
      if (kt < qt) {
        stage(cur ^ 1, kt + 1);
        asm volatile("s_waitcnt vmcnt(8)" ::: "memory");  // kt's 8 loads done; kt+1's in flight
      } else {
        asm volatile("s_waitcnt vmcnt(0)" ::: "memory");
      }
      __builtin_amdgcn_s_barrier();
      __builtin_amdgcn_sched_barrier(0);

      // ---- QK^T: S[16q][64k] ----
      f32x4 sacc[4];
#pragma unroll
      for (int n = 0; n < 4; ++n) sacc[n] = (f32x4){0.f, 0.f, 0.f, 0.f};
#pragma unroll
      for (int ks = 0; ks < 4; ++ks) {
        const int x = ks * 64 + g * 16;
#pragma unroll
        for (int n = 0; n < 4; ++n) {
          const int kl = n * 16 + lq;
          short8 bk = *(const short8*)((const char*)Ks[cur] + kl * 256 + (x ^ ((kl & 7) << 4)));
          sacc[n] = __builtin_amdgcn_mfma_f32_16x16x32_bf16(aq[ks], bk, sacc[n], 0, 0, 0);
        }
      }
#pragma unroll
      for (int n = 0; n < 4; ++n)
#pragma unroll
        for (int j = 0; j < 4; ++j) sacc[n][j] *= scale;
      if (kt == qt) {  // diagonal: causal mask
#pragma unroll
        for (int n = 0; n < 4; ++n) {
          const int key = k0 + n * 16 + lq;
#pragma unroll
          for (int j = 0; j < 4; ++j) {
            const int qrow = q0 + wid * 16 + g * 4 + j;
            if (key > qrow) sacc[n][j] = -3e38f;
          }
        }
      }
      // ---- online softmax (rows j, 16-lane group reduce) ----
      float tmax[4];
#pragma unroll
      for (int j = 0; j < 4; ++j)
        tmax[j] = fmaxf(fmaxf(sacc[0][j], sacc[1][j]), fmaxf(sacc[2][j], sacc[3][j]));
#pragma unroll
      for (int off = 1; off < 16; off <<= 1)
#pragma unroll
        for (int j = 0; j < 4; ++j) tmax[j] = fmaxf(tmax[j], __shfl_xor(tmax[j], off));
      float mn[4], fr[4];
#pragma unroll
      for (int j = 0; j < 4; ++j) {
        mn[j] = fmaxf(sm[j], tmax[j]);
        fr[j] = __expf(sm[j] - mn[j]);
        sm[j] = mn[j];
      }
      f32x4 p[4];
#pragma unroll
      for (int n = 0; n < 4; ++n)
#pragma unroll
        for (int j = 0; j < 4; ++j) p[n][j] = __expf(sacc[n][j] - mn[j]);
      float psum[4];
#pragma unroll
      for (int j = 0; j < 4; ++j) psum[j] = p[0][j] + p[1][j] + p[2][j] + p[3][j];
#pragma unroll
      for (int off = 1; off < 16; off <<= 1)
#pragma unroll
        for (int j = 0; j < 4; ++j) psum[j] += __shfl_xor(psum[j], off);
#pragma unroll
      for (int j = 0; j < 4; ++j) sl[j] = sl[j] * fr[j] + psum[j];
#pragma unroll
      for (int n = 0; n < 8; ++n)
#pragma unroll
        for (int j = 0; j < 4; ++j) oacc[n][j] *= fr[j];
      // ---- P -> LDS (bf16, swizzled; per-wave region) ----
#pragma unroll
      for (int n = 0; n < 4; ++n) {
        const int col2 = (n * 16 + lq) * 2;
#pragma unroll
        for (int j = 0; j < 4; ++j) {
          const int row = g * 4 + j;
          *(ushort_t*)(Pbase + row * 128 + (col2 ^ ((row & 7) << 4))) = f2bf(p[n][j]);
        }
      }
      // ---- PV: O[16q][128d] += P[16q][64k] * Vt[128d][64k]^T ----
#pragma unroll
      for (int ks2 = 0; ks2 < 2; ++ks2) {
        const int x = ks2 * 64 + g * 16;
        short8 pa = *(const short8*)(Pbase + lq * 128 + (x ^ ((lq & 7) << 4)));
#pragma unroll
        for (int nd = 0; nd < 8; ++nd) {
          const int dl = nd * 16 + lq;
          short8 vb = *(const short8*)((const char*)Vts[cur] + dl * 128 + (x ^ ((dl & 7) << 4)));
          oacc[nd] = __builtin_amdgcn_mfma_f32_16x16x32_bf16(pa, vb, oacc[nd], 0, 0, 0);
        }
      }
      __builtin_amdgcn_sched_barrier(0);
      __builtin_amdgcn_s_barrier();  // all waves done with buf[cur] before restage
      cur ^= 1;
    }
    // ---- epilogue for this q-tile ----
    float inv[4];
#pragma unroll
    for (int j = 0; j < 4; ++j) inv[j] = 1.f / sl[j];
#pragma unroll
    for (int nd = 0; nd < 8; ++nd) {
      const int d = nd * 16 + lq;
#pragma unroll
      for (int j = 0; j < 4; ++j) {
        const long row = (long)b * 2048 + q0 + wid * 16 + g * 4 + j;
        out[row * 2048 + h * 128 + d] = f2bf(oacc[nd][j] * inv[j]);
      }
    }
  }
}

// ---------------- launch ----------------
// Workspace: EXACTLY 101,711,872 B (round-3-proven bound). vt (16.8MB) lives in
// the dead small-weight region [16.8MB, 33.5MB).
extern "C" void kernel_launch(void* const* d_in, const int* in_sizes, int n_in,
                              void* d_out, int out_size, void* d_ws, size_t ws_size,
                              hipStream_t stream) {
  const float* x      = (const float*)d_in[0];
  const float* fcos   = (const float*)d_in[1];
  const float* fsin   = (const float*)d_in[2];
  const float* w_cq   = (const float*)d_in[3];
  const float* w_dqn  = (const float*)d_in[4];
  const float* w_dqr  = (const float*)d_in[5];
  const float* w_ckv  = (const float*)d_in[6];
  const float* w_dkn  = (const float*)d_in[7];
  const float* w_dv   = (const float*)d_in[8];
  const float* w_kr   = (const float*)d_in[9];
  const float* w_proj = (const float*)d_in[10];
  const float* qnw    = (const float*)d_in[11];
  const float* kvnw   = (const float*)d_in[12];
  float* out = (float*)d_out;

  char* ws = (char*)d_ws;
  ushort_t* x_bf     = (ushort_t*)(ws + 0);
  ushort_t* wcq_bf   = (ushort_t*)(ws + 16777216);
  ushort_t* wdqn_bf  = (ushort_t*)(ws + 23068672);
  ushort_t* wdqr_bf  = (ushort_t*)(ws + 26214400);
  ushort_t* wckv_bf  = (ushort_t*)(ws + 29360128);
  ushort_t* wdkn_bf  = (ushort_t*)(ws + 31457280);
  ushort_t* wdv_bf   = (ushort_t*)(ws + 32505856);
  ushort_t* wpr_bf   = (ushort_t*)(ws + 34603008);
  ushort_t* cq_bf    = (ushort_t*)(ws + 42991616);  // CQ region
  ushort_t* krope_bf = (ushort_t*)(ws + 42991616);  //   after cq dead
  ushort_t* kraw_bf  = (ushort_t*)(ws + 51380224);  //   after cq dead
  ushort_t* qrs_bf   = (ushort_t*)(ws + 51904512);  //   after cq dead
  ushort_t* ckv_bf   = (ushort_t*)(ws + 55574528);  // CKVNQ region
  ushort_t* wkr_bf   = (ushort_t*)(ws + 55574528);  //   after ckv dead
  ushort_t* nq_bf    = (ushort_t*)(ws + 59768832);  //   CKVNQ + 4.2MB
  ushort_t* attn_bf  = (ushort_t*)(ws + 55574528);  //   after nq/wkr dead
  ushort_t* nkv_bf   = (ushort_t*)(ws + 72351744);
  ushort_t* qnope_bf = (ushort_t*)(ws + 76546048);
  ushort_t* qr_bf    = (ushort_t*)(ws + 0);         // X region, after x_bf dead
  ushort_t* knope_bf = (ushort_t*)(ws + 8388608);   // X region + 8.4MB
  ushort_t* v_bf     = (ushort_t*)(ws + 84934656);
  ushort_t* vt_bf    = (ushort_t*)(ws + 16777216);  // dead weight region (16.8MB)

  // 1. converts
  cvt_f32_bf16<<<8192, 256, 0, stream>>>(x, x_bf, 8388608);
  cvt_f32_bf16<<<3072, 256, 0, stream>>>(w_cq, wcq_bf, 3145728);
  cvt_f32_bf16<<<1536, 256, 0, stream>>>(w_dqn, wdqn_bf, 1572864);
  cvt_f32_bf16<<<1536, 256, 0, stream>>>(w_dqr, wdqr_bf, 1572864);
  cvt_f32_bf16<<<1024, 256, 0, stream>>>(w_ckv, wckv_bf, 1048576);
  cvt_f32_bf16<<<512, 256, 0, stream>>>(w_dkn, wdkn_bf, 524288);
  cvt_f32_bf16<<<1024, 256, 0, stream>>>(w_dv, wdv_bf, 1048576);
  cvt_f32_bf16<<<4096, 256, 0, stream>>>(w_proj, wpr_bf, 4194304);

  // 2. ckv = x @ w_ckv^T ; rmsnorm
  gemm_bt<1><<<dim3(4, 32), 256, 0, stream>>>(x_bf, wckv_bf, ckv_bf, 4096, 512, 2048);
  rmsnorm_bf<<<4096, 256, 0, stream>>>(ckv_bf, kvnw, nkv_bf, 512);
  // 3. wkr convert into freed ckv slot
  cvt_f32_bf16<<<128, 256, 0, stream>>>(w_kr, wkr_bf, 131072);
  // 4. cq = x @ w_cq^T ; rmsnorm
  gemm_bt<1><<<dim3(12, 32), 256, 0, stream>>>(x_bf, wcq_bf, cq_bf, 4096, 1536, 2048);
  rmsnorm_bf<<<4096, 256, 0, stream>>>(cq_bf, qnw, nq_bf, 1536);
  // 5. kraw = x @ w_kr^T  (x_bf dead after)
  gemm_bt<1><<<dim3(1, 32), 256, 0, stream>>>(x_bf, wkr_bf, kraw_bf, 4096, 64, 2048);
  // 6. q projections  (nq dead after)
  gemm_bt<1><<<dim3(8, 32), 256, 0, stream>>>(nq_bf, wdqn_bf, qnope_bf, 4096, 1024, 1536);
  gemm_bt<1><<<dim3(8, 32), 256, 0, stream>>>(nq_bf, wdqr_bf, qr_bf, 4096, 1024, 1536);
  // 7. kv projections  (nkv dead after; weights dead after)
  gemm_bt<1><<<dim3(8, 32), 256, 0, stream>>>(nkv_bf, wdkn_bf, knope_bf, 4096, 1024, 512);
  gemm_bt<1><<<dim3(16, 32), 256, 0, stream>>>(nkv_bf, wdv_bf, v_bf, 4096, 2048, 512);
  // 8. V transpose into dead weight region
  transpose_v<<<dim3(32, 32), 256, 0, stream>>>(v_bf, vt_bf);
  // 9. swapped rope (per reference)
  rope_kernel<<<8192, 256, 0, stream>>>(qr_bf, krope_bf, fcos, fsin, 16);
  rope_kernel<<<512, 256, 0, stream>>>(kraw_bf, qrs_bf, fcos, fsin, 1);
  // 10. MFMA flash attention v2 (paired q-tiles, double-buffered)
  attn_mfma<<<dim3(16, 32), 256, 0, stream>>>(qnope_bf, qrs_bf, knope_bf, krope_bf, vt_bf, attn_bf);
  // 11. final projection (fp32 out)
  gemm_bt<0><<<dim3(16, 32), 256, 0, stream>>>(attn_bf, wpr_bf, out, 4096, 2048, 2048);
}

// Round 7
// 437.636 us; speedup vs baseline: 70.4565x; 1.0541x over previous
//
#include <hip/hip_runtime.h>

typedef __attribute__((ext_vector_type(4))) float f32x4;
typedef __attribute__((ext_vector_type(8))) short short8;
typedef unsigned short ushort_t;

__device__ __forceinline__ float bf2f(ushort_t u) {
  unsigned int i = ((unsigned int)u) << 16;
  return __builtin_bit_cast(float, i);
}
__device__ __forceinline__ ushort_t f2bf(float f) {
  unsigned int x = __builtin_bit_cast(unsigned int, f);
  unsigned int r = (x + 0x7FFFu + ((x >> 16) & 1u)) >> 16;
  return (ushort_t)r;
}

// ---------------- fused fp32 -> bf16 convert: all 9 inputs in one launch ----------------
// Segment sizes (elems/1024 = blocks): x 8192 | wcq 3072 | wdqn 1536 | wdqr 1536 |
// wckv 1024 | wdkn 512 | wdv 1024 | wkr 128 | wproj 4096 ; total 21120 blocks.
__global__ __launch_bounds__(256)
void cvt_all(const float* __restrict__ x, const float* __restrict__ wcq,
             const float* __restrict__ wdqn, const float* __restrict__ wdqr,
             const float* __restrict__ wckv, const float* __restrict__ wdkn,
             const float* __restrict__ wdv, const float* __restrict__ wkr,
             const float* __restrict__ wpr,
             ushort_t* ox, ushort_t* owcq, ushort_t* owdqn, ushort_t* owdqr,
             ushort_t* owckv, ushort_t* owdkn, ushort_t* owdv, ushort_t* owkr,
             ushort_t* owpr) {
  int bid = blockIdx.x;
  const float* in; ushort_t* out;
  if (bid < 8192)       { in = x;    out = ox;    }
  else if (bid < 11264) { in = wcq;  out = owcq;  bid -= 8192;  }
  else if (bid < 12800) { in = wdqn; out = owdqn; bid -= 11264; }
  else if (bid < 14336) { in = wdqr; out = owdqr; bid -= 12800; }
  else if (bid < 15360) { in = wckv; out = owckv; bid -= 14336; }
  else if (bid < 15872) { in = wdkn; out = owdkn; bid -= 15360; }
  else if (bid < 16896) { in = wdv;  out = owdv;  bid -= 15872; }
  else if (bid < 17024) { in = wkr;  out = owkr;  bid -= 16896; }
  else                  { in = wpr;  out = owpr;  bid -= 17024; }
  const long i = ((long)bid * 256 + threadIdx.x) * 4;
  float4 v = *(const float4*)(in + i);
  ushort4 o;
  o.x = f2bf(v.x); o.y = f2bf(v.y); o.z = f2bf(v.z); o.w = f2bf(v.w);
  *(ushort4*)(out + i) = o;
}

// ---------------- bf16 MFMA GEMM: C(MxN) = A(MxK) * B(NxK)^T ----------------
// 128x128 tile, BK=64, 4 waves (2x2). m97 structure (round-4 verified).
template <int OUT_BF16>
__global__ __launch_bounds__(256)
void gemm_bt(const ushort_t* __restrict__ A, const ushort_t* __restrict__ B,
             void* __restrict__ Cv, int M, int N, int K) {
  __shared__ __align__(16) ushort_t As[128 * 64];
  __shared__ __align__(16) ushort_t Bs[128 * 64];
  const int tid = threadIdx.x;
  const int lane = tid & 63;
  const int wid = tid >> 6;
  const int m0 = blockIdx.y * 128;
  const int n0 = blockIdx.x * 128;
  const int wm = (wid >> 1) * 64;
  const int wn = (wid & 1) * 64;

  f32x4 acc[4][4];
#pragma unroll
  for (int m = 0; m < 4; ++m)
#pragma unroll
    for (int n = 0; n < 4; ++n) acc[m][n] = (f32x4){0.f, 0.f, 0.f, 0.f};

  const int ktiles = K >> 6;
  for (int kt = 0; kt < ktiles; ++kt) {
    const int k0 = kt << 6;
    __syncthreads();
#pragma unroll
    for (int i = 0; i < 4; ++i) {
      const int chunk = (i * 4 + wid) * 1024;
      const int o = chunk + lane * 16;
      const int row = o >> 7;
      const int cb = o & 127;
      const ushort_t* src = A + (long)(m0 + row) * K + (k0 + (cb >> 1));
      __builtin_amdgcn_global_load_lds((const __attribute__((address_space(1))) unsigned int*)src,
                                       (__attribute__((address_space(3))) unsigned int*)((char*)As + chunk),
                                       16, 0, 0);
    }
#pragma unroll
    for (int i = 0; i < 4; ++i) {
      const int chunk = (i * 4 + wid) * 1024;
      const int o = chunk + lane * 16;
      const int row = o >> 7;
      const int cb = o & 127;
      int brow = n0 + row;
      if (brow > N - 1) brow = N - 1;
      const ushort_t* src = B + (long)brow * K + (k0 + (cb >> 1));
      __builtin_amdgcn_global_load_lds((const __attribute__((address_space(1))) unsigned int*)src,
                                       (__attribute__((address_space(3))) unsigned int*)((char*)Bs + chunk),
                                       16, 0, 0);
    }
    __syncthreads();
#pragma unroll
    for (int kk = 0; kk < 2; ++kk) {
      const int kb = kk * 32 + ((lane >> 4) << 3);
      short8 a[4], b[4];
#pragma unroll
      for (int m = 0; m < 4; ++m)
        a[m] = *(const short8*)(As + (wm + m * 16 + (lane & 15)) * 64 + kb);
#pragma unroll
      for (int n = 0; n < 4; ++n)
        b[n] = *(const short8*)(Bs + (wn + n * 16 + (lane & 15)) * 64 + kb);
#pragma unroll
      for (int m = 0; m < 4; ++m)
#pragma unroll
        for (int n = 0; n < 4; ++n)
          acc[m][n] = __builtin_amdgcn_mfma_f32_16x16x32_bf16(a[m], b[n], acc[m][n], 0, 0, 0);
    }
  }
  const int rb = m0 + wm + ((lane >> 4) << 2);
  const int cbase = n0 + wn + (lane & 15);
#pragma unroll
  for (int m = 0; m < 4; ++m)
#pragma unroll
    for (int n = 0; n < 4; ++n) {
      const int c = cbase + n * 16;
      if (c < N) {
#pragma unroll
        for (int j = 0; j < 4; ++j) {
          const long r = rb + m * 16 + j;
          if (OUT_BF16)
            ((ushort_t*)Cv)[r * N + c] = f2bf(acc[m][n][j]);
          else
            ((float*)Cv)[r * N + c] = acc[m][n][j];
        }
      }
    }
}

// ---------------- RMSNorm row kernel: bf16 in -> bf16 out ----------------
__global__ __launch_bounds__(256)
void rmsnorm_bf(const ushort_t* __restrict__ in, const float* __restrict__ w,
                ushort_t* __restrict__ out, int R) {
  const long row = blockIdx.x;
  const ushort_t* x = in + row * R;
  const int tid = threadIdx.x;
  float ss = 0.f;
  for (int i = tid; i < R; i += 256) { float v = bf2f(x[i]); ss += v * v; }
#pragma unroll
  for (int off = 32; off; off >>= 1) ss += __shfl_xor(ss, off);
  __shared__ float warr[4];
  if ((tid & 63) == 0) warr[tid >> 6] = ss;
  __syncthreads();
  const float tot = warr[0] + warr[1] + warr[2] + warr[3];
  const float rs = rsqrtf(tot / (float)R + 1e-6f);
  for (int i = tid; i < R; i += 256) out[row * R + i] = f2bf(bf2f(x[i]) * rs * w[i]);
}

// ---------------- fused RoPE: both tensors in one launch ----------------
// blocks [0,8192): qr(16 heads)->krope ; [8192,8704): kraw(1 head)->qrs
__global__ __launch_bounds__(256)
void rope_both(const ushort_t* __restrict__ qr, ushort_t* __restrict__ krope,
               const ushort_t* __restrict__ kraw, ushort_t* __restrict__ qrs,
               const float* __restrict__ fc, const float* __restrict__ fs) {
  int bid = blockIdx.x;
  const ushort_t* in; ushort_t* out; int heads;
  if (bid < 8192) { in = qr; out = krope; heads = 16; }
  else            { in = kraw; out = qrs; heads = 1; bid -= 8192; }
  const int idx = bid * 256 + threadIdx.x;
  const int i = idx & 31;
  const int rest = idx >> 5;
  const int hh = rest % heads;
  const int row = rest / heads;
  const int srow = row & 2047;
  const float c = fc[srow * 32 + i];
  const float s = fs[srow * 32 + i];
  const long base = (long)row * heads * 64 + hh * 64 + 2 * i;
  const float x0 = bf2f(in[base]);
  const float x1 = bf2f(in[base + 1]);
  out[base] = f2bf(x0 * c - x1 * s);
  out[base + 1] = f2bf(x0 * s + x1 * c);
}

// ---------------- V transpose: v[row][h*128+d] -> vt[bh][d][s] ----------------
__global__ __launch_bounds__(256)
void transpose_v(const ushort_t* __restrict__ v, ushort_t* __restrict__ vt) {
  __shared__ __align__(16) ushort_t Ts[64 * 128];  // byte(s,d)=s*256+((2d)^((s&15)<<4))
  const int t = threadIdx.x;
  const int bh = blockIdx.y;
  const int b = bh >> 4, h = bh & 15;
  const int s0 = blockIdx.x * 64;
#pragma unroll
  for (int i = 0; i < 4; ++i) {
    const int c = t + 256 * i;
    const int si = c >> 4;
    const int xb = (c & 15) * 16;
    const long src = ((long)b * 2048 + s0 + si) * 2048 + h * 128 + (xb >> 1);
    short8 val = *(const short8*)(v + src);
    *(short8*)((char*)Ts + si * 256 + (xb ^ ((si & 15) << 4))) = val;
  }
  __syncthreads();
  const int d = (t & 63) + ((t >> 7) << 6);
  const int scb = ((t >> 6) & 1) * 4;
#pragma unroll
  for (int i = 0; i < 4; ++i) {
    const int sc = scb + i;
    short8 val;
#pragma unroll
    for (int j = 0; j < 8; ++j) {
      const int s = sc * 8 + j;
      val[j] = (short)*(const ushort_t*)((const char*)Ts + s * 256 + ((2 * d) ^ ((s & 15) << 4)));
    }
    *(short8*)(vt + ((long)bh * 128 + d) * 2048 + s0 + sc * 8) = val;
  }
}

// ---------------- MFMA flash attention v3 ----------------
// Grid (bh, pair): wgid%8 = bh%8 -> all 16 pair-blocks of one bh share an XCD L2
// (K/V working set ~1MB/bh, 4 bh/XCD ~ 4MB L2). T5 setprio around MFMA clusters;
// T13 defer-max (THR=8) skips O-rescale; scale folded into exp via FMA.
__global__ __launch_bounds__(256)
void attn_mfma(const ushort_t* __restrict__ qn, const ushort_t* __restrict__ qrs,
               const ushort_t* __restrict__ kn, const ushort_t* __restrict__ kr,
               const ushort_t* __restrict__ vt, ushort_t* __restrict__ out) {
  __shared__ __align__(16) ushort_t Ks[2][8192];   // [64 k][128 d], rows 256B, swizzled
  __shared__ __align__(16) ushort_t Vts[2][8192];  // [128 d][64 s], rows 128B, swizzled
  __shared__ __align__(16) ushort_t Ps[4096];      // per-wave [16 q][64 k], swizzled
  const int tid = threadIdx.x, lane = tid & 63, wid = tid >> 6;
  const int g = lane >> 4, lq = lane & 15;
  const int bh = blockIdx.x, b = bh >> 4, h = bh & 15;
  const float scale = 0.08838834764831845f;  // 1/sqrt(128)
  char* Pbase = (char*)Ps + wid * 2048;

  auto stage = [&](int bsel, int kt) {
    const int k0s = kt * 64;
#pragma unroll
    for (int i = 0; i < 4; ++i) {
      const int cc = wid * 4 + i;
      const int o = cc * 1024 + lane * 16;
      {
        const int row = o >> 8;
        const int dK = ((o & 255) ^ ((row & 7) << 4)) >> 1;
        const long krow = (long)b * 2048 + k0s + row;
        const ushort_t* srcK = (dK < 64) ? (kn + krow * 1024 + h * 64 + dK)
                                         : (kr + krow * 1024 + h * 64 + (dK - 64));
        __builtin_amdgcn_global_load_lds((const __attribute__((address_space(1))) unsigned int*)srcK,
            (__attribute__((address_space(3))) unsigned int*)((char*)Ks[bsel] + cc * 1024), 16, 0, 0);
      }
      {
        const int dr = o >> 7;
        const int se = ((o & 127) ^ ((dr & 7) << 4)) >> 1;
        const ushort_t* srcV = vt + ((long)bh * 128 + dr) * 2048 + k0s + se;
        __builtin_amdgcn_global_load_lds((const __attribute__((address_space(1))) unsigned int*)srcV,
            (__attribute__((address_space(3))) unsigned int*)((char*)Vts[bsel] + cc * 1024), 16, 0, 0);
      }
    }
  };

  const int pair = blockIdx.y;
  for (int half = 0; half < 2; ++half) {
    const int qt = half ? (31 - pair) : pair;
    const int q0 = qt * 64;
    short8 aq[4];
    {
      const long grow = (long)b * 2048 + q0 + wid * 16 + lq;
#pragma unroll
      for (int ks = 0; ks < 4; ++ks) {
        const int d = ks * 32 + g * 8;
        const ushort_t* src = (d < 64) ? (qn + grow * 1024 + h * 64 + d)
                                       : (qrs + grow * 64 + (d - 64));
        aq[ks] = *(const short8*)src;
      }
    }
    f32x4 oacc[8];
#pragma unroll
    for (int n = 0; n < 8; ++n) oacc[n] = (f32x4){0.f, 0.f, 0.f, 0.f};
    float sm[4] = {-3e38f, -3e38f, -3e38f, -3e38f};
    float sl[4] = {0.f, 0.f, 0.f, 0.f};

    int cur = 0;
    stage(0, 0);
    for (int kt = 0; kt <= qt; ++kt) {
      const int k0 = kt * 64;
      if (kt < qt) {
        stage(cur ^ 1, kt + 1);
        asm volatile("s_waitcnt vmcnt(8)" ::: "memory");  // kt's 8 loads done; kt+1's in flight
      } else {
        asm volatile("s_waitcnt vmcnt(0)" ::: "memory");
      }
      __builtin_amdgcn_s_barrier();
      __builtin_amdgcn_sched_barrier(0);

      // ---- QK^T: S[16q][64k] (raw, scale folded into exp) ----
      f32x4 sacc[4];
#pragma unroll
      for (int n = 0; n < 4; ++n) sacc[n] = (f32x4){0.f, 0.f, 0.f, 0.f};
      __builtin_amdgcn_s_setprio(1);
#pragma unroll
      for (int ks = 0; ks < 4; ++ks) {
        const int x = ks * 64 + g * 16;
#pragma unroll
        for (int n = 0; n < 4; ++n) {
          const int kl = n * 16 + lq;
          short8 bk = *(const short8*)((const char*)Ks[cur] + kl * 256 + (x ^ ((kl & 7) << 4)));
          sacc[n] = __builtin_amdgcn_mfma_f32_16x16x32_bf16(aq[ks], bk, sacc[n], 0, 0, 0);
        }
      }
      __builtin_amdgcn_s_setprio(0);
      if (kt == qt) {  // diagonal: causal mask (pre-scale domain)
#pragma unroll
        for (int n = 0; n < 4; ++n) {
          const int key = k0 + n * 16 + lq;
#pragma unroll
          for (int j = 0; j < 4; ++j) {
            const int qrow = q0 + wid * 16 + g * 4 + j;
            if (key > qrow) sacc[n][j] = -3e38f;
          }
        }
      }
      // ---- online softmax with defer-max (T13) ----
      float tmax[4];
#pragma unroll
      for (int j = 0; j < 4; ++j)
        tmax[j] = fmaxf(fmaxf(sacc[0][j], sacc[1][j]), fmaxf(sacc[2][j], sacc[3][j]));
#pragma unroll
      for (int off = 1; off < 16; off <<= 1)
#pragma unroll
        for (int j = 0; j < 4; ++j) tmax[j] = fmaxf(tmax[j], __shfl_xor(tmax[j], off));
      bool need = false;
#pragma unroll
      for (int j = 0; j < 4; ++j) {
        tmax[j] *= scale;
        need = need || (tmax[j] > sm[j] + 8.f);
      }
      if (__any(need)) {
#pragma unroll
        for (int j = 0; j < 4; ++j) {
          const float mn = fmaxf(sm[j], tmax[j]);
          const float fr = __expf(sm[j] - mn);
          sm[j] = mn;
          sl[j] *= fr;
#pragma unroll
          for (int n = 0; n < 8; ++n) oacc[n][j] *= fr;
        }
      }
      f32x4 p[4];
#pragma unroll
      for (int n = 0; n < 4; ++n)
#pragma unroll
        for (int j = 0; j < 4; ++j)
          p[n][j] = __expf(__builtin_fmaf(sacc[n][j], scale, -sm[j]));
      float psum[4];
#pragma unroll
      for (int j = 0; j < 4; ++j) psum[j] = p[0][j] + p[1][j] + p[2][j] + p[3][j];
#pragma unroll
      for (int off = 1; off < 16; off <<= 1)
#pragma unroll
        for (int j = 0; j < 4; ++j) psum[j] += __shfl_xor(psum[j], off);
#pragma unroll
      for (int j = 0; j < 4; ++j) sl[j] += psum[j];
      // ---- P -> LDS (bf16, swizzled; per-wave region) ----
#pragma unroll
      for (int n = 0; n < 4; ++n) {
        const int col2 = (n * 16 + lq) * 2;
#pragma unroll
        for (int j = 0; j < 4; ++j) {
          const int row = g * 4 + j;
          *(ushort_t*)(Pbase + row * 128 + (col2 ^ ((row & 7) << 4))) = f2bf(p[n][j]);
        }
      }
      // ---- PV: O[16q][128d] += P[16q][64k] * Vt[128d][64k]^T ----
      __builtin_amdgcn_s_setprio(1);
#pragma unroll
      for (int ks2 = 0; ks2 < 2; ++ks2) {
        const int x = ks2 * 64 + g * 16;
        short8 pa = *(const short8*)(Pbase + lq * 128 + (x ^ ((lq & 7) << 4)));
#pragma unroll
        for (int nd = 0; nd < 8; ++nd) {
          const int dl = nd * 16 + lq;
          short8 vb = *(const short8*)((const char*)Vts[cur] + dl * 128 + (x ^ ((dl & 7) << 4)));
          oacc[nd] = __builtin_amdgcn_mfma_f32_16x16x32_bf16(pa, vb, oacc[nd], 0, 0, 0);
        }
      }
      __builtin_amdgcn_s_setprio(0);
      __builtin_amdgcn_sched_barrier(0);
      __builtin_amdgcn_s_barrier();  // all waves done with buf[cur] before restage
      cur ^= 1;
    }
    // ---- epilogue for this q-tile ----
    float inv[4];
#pragma unroll
    for (int j = 0; j < 4; ++j) inv[j] = 1.f / sl[j];
#pragma unroll
    for (int nd = 0; nd < 8; ++nd) {
      const int d = nd * 16 + lq;
#pragma unroll
      for (int j = 0; j < 4; ++j) {
        const long row = (long)b * 2048 + q0 + wid * 16 + g * 4 + j;
        out[row * 2048 + h * 128 + d] = f2bf(oacc[nd][j] * inv[j]);
      }
    }
  }
}

// ---------------- launch ----------------
// Workspace: EXACTLY 101,711,872 B (round-3-proven bound).
// wkr_bf now lives at the start of the V region (84934656): read at step 4
// (kraw gemm), dead before v_bf is written at step 6.
extern "C" void kernel_launch(void* const* d_in, const int* in_sizes, int n_in,
                              void* d_out, int out_size, void* d_ws, size_t ws_size,
                              hipStream_t stream) {
  const float* x      = (const float*)d_in[0];
  const float* fcos   = (const float*)d_in[1];
  const float* fsin   = (const float*)d_in[2];
  const float* w_cq   = (const float*)d_in[3];
  const float* w_dqn  = (const float*)d_in[4];
  const float* w_dqr  = (const float*)d_in[5];
  const float* w_ckv  = (const float*)d_in[6];
  const float* w_dkn  = (const float*)d_in[7];
  const float* w_dv   = (const float*)d_in[8];
  const float* w_kr   = (const float*)d_in[9];
  const float* w_proj = (const float*)d_in[10];
  const float* qnw    = (const float*)d_in[11];
  const float* kvnw   = (const float*)d_in[12];
  float* out = (float*)d_out;

  char* ws = (char*)d_ws;
  ushort_t* x_bf     = (ushort_t*)(ws + 0);
  ushort_t* wcq_bf   = (ushort_t*)(ws + 16777216);
  ushort_t* wdqn_bf  = (ushort_t*)(ws + 23068672);
  ushort_t* wdqr_bf  = (ushort_t*)(ws + 26214400);
  ushort_t* wckv_bf  = (ushort_t*)(ws + 29360128);
  ushort_t* wdkn_bf  = (ushort_t*)(ws + 31457280);
  ushort_t* wdv_bf   = (ushort_t*)(ws + 32505856);
  ushort_t* wpr_bf   = (ushort_t*)(ws + 34603008);
  ushort_t* cq_bf    = (ushort_t*)(ws + 42991616);  // CQ region
  ushort_t* krope_bf = (ushort_t*)(ws + 42991616);  //   after cq dead
  ushort_t* kraw_bf  = (ushort_t*)(ws + 51380224);  //   after cq dead
  ushort_t* qrs_bf   = (ushort_t*)(ws + 51904512);  //   after cq dead
  ushort_t* ckv_bf   = (ushort_t*)(ws + 55574528);  // CKVNQ region
  ushort_t* nq_bf    = (ushort_t*)(ws + 59768832);  //   CKVNQ + 4.2MB
  ushort_t* attn_bf  = (ushort_t*)(ws + 55574528);  //   after nq dead
  ushort_t* nkv_bf   = (ushort_t*)(ws + 72351744);
  ushort_t* qnope_bf = (ushort_t*)(ws + 76546048);
  ushort_t* qr_bf    = (ushort_t*)(ws + 0);         // X region, after x_bf dead
  ushort_t* knope_bf = (ushort_t*)(ws + 8388608);   // X region + 8.4MB
  ushort_t* v_bf     = (ushort_t*)(ws + 84934656);  // V region
  ushort_t* wkr_bf   = (ushort_t*)(ws + 84934656);  //   before v_bf written
  ushort_t* vt_bf    = (ushort_t*)(ws + 16777216);  // dead weight region (16.8MB)

  // 1. all converts in one launch (wkr -> V region, safe: v_bf written at step 6)
  cvt_all<<<21120, 256, 0, stream>>>(x, w_cq, w_dqn, w_dqr, w_ckv, w_dkn, w_dv, w_kr, w_proj,
                                     x_bf, wcq_bf, wdqn_bf, wdqr_bf, wckv_bf, wdkn_bf,
                                     wdv_bf, wkr_bf, wpr_bf);
  // 2. ckv = x @ w_ckv^T ; rmsnorm
  gemm_bt<1><<<dim3(4, 32), 256, 0, stream>>>(x_bf, wckv_bf, ckv_bf, 4096, 512, 2048);
  rmsnorm_bf<<<4096, 256, 0, stream>>>(ckv_bf, kvnw, nkv_bf, 512);
  // 3. cq = x @ w_cq^T ; rmsnorm
  gemm_bt<1><<<dim3(12, 32), 256, 0, stream>>>(x_bf, wcq_bf, cq_bf, 4096, 1536, 2048);
  rmsnorm_bf<<<4096, 256, 0, stream>>>(cq_bf, qnw, nq_bf, 1536);
  // 4. kraw = x @ w_kr^T  (x_bf dead after; wkr dead after)
  gemm_bt<1><<<dim3(1, 32), 256, 0, stream>>>(x_bf, wkr_bf, kraw_bf, 4096, 64, 2048);
  // 5. q projections  (nq dead after)
  gemm_bt<1><<<dim3(8, 32), 256, 0, stream>>>(nq_bf, wdqn_bf, qnope_bf, 4096, 1024, 1536);
  gemm_bt<1><<<dim3(8, 32), 256, 0, stream>>>(nq_bf, wdqr_bf, qr_bf, 4096, 1024, 1536);
  // 6. kv projections  (nkv dead after; v_bf overwrites wkr slot - wkr dead)
  gemm_bt<1><<<dim3(8, 32), 256, 0, stream>>>(nkv_bf, wdkn_bf, knope_bf, 4096, 1024, 512);
  gemm_bt<1><<<dim3(16, 32), 256, 0, stream>>>(nkv_bf, wdv_bf, v_bf, 4096, 2048, 512);
  // 7. V transpose into dead weight region
  transpose_v<<<dim3(32, 32), 256, 0, stream>>>(v_bf, vt_bf);
  // 8. fused rope (qr->krope heads=16 ; kraw->qrs heads=1)
  rope_both<<<8704, 256, 0, stream>>>(qr_bf, krope_bf, kraw_bf, qrs_bf, fcos, fsin);
  // 9. MFMA flash attention v3 (grid = (bh, pair) for XCD L2 affinity)
  attn_mfma<<<dim3(32, 16), 256, 0, stream>>>(qnope_bf, qrs_bf, knope_bf, krope_bf, vt_bf, attn_bf);
  // 10. final projection (fp32 out)
  gemm_bt<0><<<dim3(16, 32), 256, 0, stream>>>(attn_bf, wpr_bf, out, 4096, 2048, 2048);
}

// Round 8
// 345.124 us; speedup vs baseline: 89.3429x; 1.2681x over previous
//
#include <hip/hip_runtime.h>

typedef __attribute__((ext_vector_type(4))) float f32x4;
typedef __attribute__((ext_vector_type(8))) short short8;
typedef unsigned short ushort_t;

__device__ __forceinline__ float bf2f(ushort_t u) {
  unsigned int i = ((unsigned int)u) << 16;
  return __builtin_bit_cast(float, i);
}
__device__ __forceinline__ ushort_t f2bf(float f) {
  unsigned int x = __builtin_bit_cast(unsigned int, f);
  unsigned int r = (x + 0x7FFFu + ((x >> 16) & 1u)) >> 16;
  return (ushort_t)r;
}

// ---------------- fused fp32 -> bf16 convert: all 9 inputs in one launch ----------------
__global__ __launch_bounds__(256)
void cvt_all(const float* __restrict__ x, const float* __restrict__ wcq,
             const float* __restrict__ wdqn, const float* __restrict__ wdqr,
             const float* __restrict__ wckv, const float* __restrict__ wdkn,
             const float* __restrict__ wdv, const float* __restrict__ wkr,
             const float* __restrict__ wpr,
             ushort_t* ox, ushort_t* owcq, ushort_t* owdqn, ushort_t* owdqr,
             ushort_t* owckv, ushort_t* owdkn, ushort_t* owdv, ushort_t* owkr,
             ushort_t* owpr) {
  int bid = blockIdx.x;
  const float* in; ushort_t* out;
  if (bid < 8192)       { in = x;    out = ox;    }
  else if (bid < 11264) { in = wcq;  out = owcq;  bid -= 8192;  }
  else if (bid < 12800) { in = wdqn; out = owdqn; bid -= 11264; }
  else if (bid < 14336) { in = wdqr; out = owdqr; bid -= 12800; }
  else if (bid < 15360) { in = wckv; out = owckv; bid -= 14336; }
  else if (bid < 15872) { in = wdkn; out = owdkn; bid -= 15360; }
  else if (bid < 16896) { in = wdv;  out = owdv;  bid -= 15872; }
  else if (bid < 17024) { in = wkr;  out = owkr;  bid -= 16896; }
  else                  { in = wpr;  out = owpr;  bid -= 17024; }
  const long i = ((long)bid * 256 + threadIdx.x) * 4;
  float4 v = *(const float4*)(in + i);
  ushort4 o;
  o.x = f2bf(v.x); o.y = f2bf(v.y); o.z = f2bf(v.z); o.w = f2bf(v.w);
  *(ushort4*)(out + i) = o;
}

// ---------------- bf16 MFMA GEMM (single-output, fp32 or bf16 out) ----------------
// 128x128 tile, BK=64, 4 waves (2x2). m97 structure (round-4 verified).
template <int OUT_BF16>
__global__ __launch_bounds__(256)
void gemm_bt(const ushort_t* __restrict__ A, const ushort_t* __restrict__ B,
             void* __restrict__ Cv, int M, int N, int K) {
  __shared__ __align__(16) ushort_t As[128 * 64];
  __shared__ __align__(16) ushort_t Bs[128 * 64];
  const int tid = threadIdx.x;
  const int lane = tid & 63;
  const int wid = tid >> 6;
  const int m0 = blockIdx.y * 128;
  const int n0 = blockIdx.x * 128;
  const int wm = (wid >> 1) * 64;
  const int wn = (wid & 1) * 64;

  f32x4 acc[4][4];
#pragma unroll
  for (int m = 0; m < 4; ++m)
#pragma unroll
    for (int n = 0; n < 4; ++n) acc[m][n] = (f32x4){0.f, 0.f, 0.f, 0.f};

  const int ktiles = K >> 6;
  for (int kt = 0; kt < ktiles; ++kt) {
    const int k0 = kt << 6;
    __syncthreads();
#pragma unroll
    for (int i = 0; i < 4; ++i) {
      const int chunk = (i * 4 + wid) * 1024;
      const int o = chunk + lane * 16;
      const int row = o >> 7;
      const int cb = o & 127;
      const ushort_t* src = A + (long)(m0 + row) * K + (k0 + (cb >> 1));
      __builtin_amdgcn_global_load_lds((const __attribute__((address_space(1))) unsigned int*)src,
                                       (__attribute__((address_space(3))) unsigned int*)((char*)As + chunk),
                                       16, 0, 0);
    }
#pragma unroll
    for (int i = 0; i < 4; ++i) {
      const int chunk = (i * 4 + wid) * 1024;
      const int o = chunk + lane * 16;
      const int row = o >> 7;
      const int cb = o & 127;
      int brow = n0 + row;
      if (brow > N - 1) brow = N - 1;
      const ushort_t* src = B + (long)brow * K + (k0 + (cb >> 1));
      __builtin_amdgcn_global_load_lds((const __attribute__((address_space(1))) unsigned int*)src,
                                       (__attribute__((address_space(3))) unsigned int*)((char*)Bs + chunk),
                                       16, 0, 0);
    }
    __syncthreads();
#pragma unroll
    for (int kk = 0; kk < 2; ++kk) {
      const int kb = kk * 32 + ((lane >> 4) << 3);
      short8 a[4], b[4];
#pragma unroll
      for (int m = 0; m < 4; ++m)
        a[m] = *(const short8*)(As + (wm + m * 16 + (lane & 15)) * 64 + kb);
#pragma unroll
      for (int n = 0; n < 4; ++n)
        b[n] = *(const short8*)(Bs + (wn + n * 16 + (lane & 15)) * 64 + kb);
#pragma unroll
      for (int m = 0; m < 4; ++m)
#pragma unroll
        for (int n = 0; n < 4; ++n)
          acc[m][n] = __builtin_amdgcn_mfma_f32_16x16x32_bf16(a[m], b[n], acc[m][n], 0, 0, 0);
    }
  }
  const int rb = m0 + wm + ((lane >> 4) << 2);
  const int cbase = n0 + wn + (lane & 15);
#pragma unroll
  for (int m = 0; m < 4; ++m)
#pragma unroll
    for (int n = 0; n < 4; ++n) {
      const int c = cbase + n * 16;
      if (c < N) {
#pragma unroll
        for (int j = 0; j < 4; ++j) {
          const long r = rb + m * 16 + j;
          if (OUT_BF16)
            ((ushort_t*)Cv)[r * N + c] = f2bf(acc[m][n][j]);
          else
            ((float*)Cv)[r * N + c] = acc[m][n][j];
        }
      }
    }
}

// ---------------- merged 3-output GEMM: same A, blocks routed to (B,C,N) ----------------
// bf16 out. Body identical to gemm_bt (verified); only n-block routing added.
__global__ __launch_bounds__(256)
void gemm_bt3(const ushort_t* __restrict__ A,
              const ushort_t* __restrict__ B0, ushort_t* __restrict__ C0, int nb0, int N0,
              const ushort_t* __restrict__ B1, ushort_t* __restrict__ C1, int nb1, int N1,
              const ushort_t* __restrict__ B2, ushort_t* __restrict__ C2, int N2,
              int K) {
  __shared__ __align__(16) ushort_t As[128 * 64];
  __shared__ __align__(16) ushort_t Bs[128 * 64];
  int bx = blockIdx.x;
  const ushort_t* Bp; ushort_t* Cp; int N;
  if (bx < nb0)            { Bp = B0; Cp = C0; N = N0; }
  else if (bx < nb0 + nb1) { Bp = B1; Cp = C1; N = N1; bx -= nb0; }
  else                     { Bp = B2; Cp = C2; N = N2; bx -= nb0 + nb1; }
  const int tid = threadIdx.x;
  const int lane = tid & 63;
  const int wid = tid >> 6;
  const int m0 = blockIdx.y * 128;
  const int n0 = bx * 128;
  const int wm = (wid >> 1) * 64;
  const int wn = (wid & 1) * 64;

  f32x4 acc[4][4];
#pragma unroll
  for (int m = 0; m < 4; ++m)
#pragma unroll
    for (int n = 0; n < 4; ++n) acc[m][n] = (f32x4){0.f, 0.f, 0.f, 0.f};

  const int ktiles = K >> 6;
  for (int kt = 0; kt < ktiles; ++kt) {
    const int k0 = kt << 6;
    __syncthreads();
#pragma unroll
    for (int i = 0; i < 4; ++i) {
      const int chunk = (i * 4 + wid) * 1024;
      const int o = chunk + lane * 16;
      const int row = o >> 7;
      const int cb = o & 127;
      const ushort_t* src = A + (long)(m0 + row) * K + (k0 + (cb >> 1));
      __builtin_amdgcn_global_load_lds((const __attribute__((address_space(1))) unsigned int*)src,
                                       (__attribute__((address_space(3))) unsigned int*)((char*)As + chunk),
                                       16, 0, 0);
    }
#pragma unroll
    for (int i = 0; i < 4; ++i) {
      const int chunk = (i * 4 + wid) * 1024;
      const int o = chunk + lane * 16;
      const int row = o >> 7;
      const int cb = o & 127;
      int brow = n0 + row;
      if (brow > N - 1) brow = N - 1;
      const ushort_t* src = Bp + (long)brow * K + (k0 + (cb >> 1));
      __builtin_amdgcn_global_load_lds((const __attribute__((address_space(1))) unsigned int*)src,
                                       (__attribute__((address_space(3))) unsigned int*)((char*)Bs + chunk),
                                       16, 0, 0);
    }
    __syncthreads();
#pragma unroll
    for (int kk = 0; kk < 2; ++kk) {
      const int kb = kk * 32 + ((lane >> 4) << 3);
      short8 a[4], b[4];
#pragma unroll
      for (int m = 0; m < 4; ++m)
        a[m] = *(const short8*)(As + (wm + m * 16 + (lane & 15)) * 64 + kb);
#pragma unroll
      for (int n = 0; n < 4; ++n)
        b[n] = *(const short8*)(Bs + (wn + n * 16 + (lane & 15)) * 64 + kb);
#pragma unroll
      for (int m = 0; m < 4; ++m)
#pragma unroll
        for (int n = 0; n < 4; ++n)
          acc[m][n] = __builtin_amdgcn_mfma_f32_16x16x32_bf16(a[m], b[n], acc[m][n], 0, 0, 0);
    }
  }
  const int rb = m0 + wm + ((lane >> 4) << 2);
  const int cbase = n0 + wn + (lane & 15);
#pragma unroll
  for (int m = 0; m < 4; ++m)
#pragma unroll
    for (int n = 0; n < 4; ++n) {
      const int c = cbase + n * 16;
      if (c < N) {
#pragma unroll
        for (int j = 0; j < 4; ++j) {
          const long r = rb + m * 16 + j;
          Cp[r * N + c] = f2bf(acc[m][n][j]);
        }
      }
    }
}

// ---------------- rmsnorm device body ----------------
__device__ __forceinline__ void rms_body(const ushort_t* x, const float* w,
                                         ushort_t* out, int R, float* warr) {
  const int tid = threadIdx.x;
  float ss = 0.f;
  for (int i = tid; i < R; i += 256) { float v = bf2f(x[i]); ss += v * v; }
#pragma unroll
  for (int off = 32; off; off >>= 1) ss += __shfl_xor(ss, off);
  if ((tid & 63) == 0) warr[tid >> 6] = ss;
  __syncthreads();
  const float tot = warr[0] + warr[1] + warr[2] + warr[3];
  const float rs = rsqrtf(tot / (float)R + 1e-6f);
  for (int i = tid; i < R; i += 256) out[i] = f2bf(bf2f(x[i]) * rs * w[i]);
}

// both rmsnorms in one launch: [0,4096) kv R=512 ; [4096,8192) q R=1536
__global__ __launch_bounds__(256)
void rmsnorm_both(const ushort_t* __restrict__ ckv, const float* __restrict__ kvnw,
                  ushort_t* __restrict__ nkv,
                  const ushort_t* __restrict__ cq, const float* __restrict__ qnw,
                  ushort_t* __restrict__ nq) {
  __shared__ float warr[4];
  const int bid = blockIdx.x;
  if (bid < 4096) rms_body(ckv + (long)bid * 512, kvnw, nkv + (long)bid * 512, 512, warr);
  else {
    const long row = bid - 4096;
    rms_body(cq + row * 1536, qnw, nq + row * 1536, 1536, warr);
  }
}

// ---------------- rope device body ----------------
__device__ __forceinline__ void rope_body(const ushort_t* in, ushort_t* out,
                                          const float* fc, const float* fs,
                                          int heads, int bid) {
  const int idx = bid * 256 + threadIdx.x;
  const int i = idx & 31;
  const int rest = idx >> 5;
  const int hh = rest % heads;
  const int row = rest / heads;
  const int srow = row & 2047;
  const float c = fc[srow * 32 + i];
  const float s = fs[srow * 32 + i];
  const long base = (long)row * heads * 64 + hh * 64 + 2 * i;
  const float x0 = bf2f(in[base]);
  const float x1 = bf2f(in[base + 1]);
  out[base] = f2bf(x0 * c - x1 * s);
  out[base + 1] = f2bf(x0 * s + x1 * c);
}

// small standalone: kraw -> qrs (heads=1), 512 blocks
__global__ __launch_bounds__(256)
void rope_kraw(const ushort_t* __restrict__ kraw, ushort_t* __restrict__ qrs,
               const float* __restrict__ fc, const float* __restrict__ fs) {
  rope_body(kraw, qrs, fc, fs, 1, blockIdx.x);
}

// ---------------- transpose_v + rope_qr merged ----------------
// [0,1024): transpose_v (s-tile = bid%32, bh = bid/32) ; [1024,9216): rope qr->krope
__global__ __launch_bounds__(256)
void tv_rope(const ushort_t* __restrict__ v, ushort_t* __restrict__ vt,
             const ushort_t* __restrict__ qr, ushort_t* __restrict__ krope,
             const float* __restrict__ fc, const float* __restrict__ fs) {
  __shared__ __align__(16) ushort_t Ts[64 * 128];
  const int bid = blockIdx.x;
  if (bid >= 1024) { rope_body(qr, krope, fc, fs, 16, bid - 1024); return; }
  const int t = threadIdx.x;
  const int bh = bid >> 5;
  const int b = bh >> 4, h = bh & 15;
  const int s0 = (bid & 31) * 64;
#pragma unroll
  for (int i = 0; i < 4; ++i) {
    const int c = t + 256 * i;
    const int si = c >> 4;
    const int xb = (c & 15) * 16;
    const long src = ((long)b * 2048 + s0 + si) * 2048 + h * 128 + (xb >> 1);
    short8 val = *(const short8*)(v + src);
    *(short8*)((char*)Ts + si * 256 + (xb ^ ((si & 15) << 4))) = val;
  }
  __syncthreads();
  const int d = (t & 63) + ((t >> 7) << 6);
  const int scb = ((t >> 6) & 1) * 4;
#pragma unroll
  for (int i = 0; i < 4; ++i) {
    const int sc = scb + i;
    short8 val;
#pragma unroll
    for (int j = 0; j < 8; ++j) {
      const int s = sc * 8 + j;
      val[j] = (short)*(const ushort_t*)((const char*)Ts + s * 256 + ((2 * d) ^ ((s & 15) << 4)));
    }
    *(short8*)(vt + ((long)bh * 128 + d) * 2048 + s0 + sc * 8) = val;
  }
}

// ---------------- MFMA flash attention v4: 8-wave blocks, 128 q-rows ----------------
// Grid (bh=32, pair=8): q-tiles of 128 rows, pairing {p, 15-p} -> 34 k-steps/block.
// K/V staged once per 128 q-rows (2x amortization vs v3); dbuf + counted vmcnt(4).
// LDS: Ks 2x16 + Vts 2x16 + Ps 16 = 80KB. wgid%8 = bh%8 keeps XCD L2 affinity.
__global__ __launch_bounds__(512)
void attn_mfma(const ushort_t* __restrict__ qn, const ushort_t* __restrict__ qrs,
               const ushort_t* __restrict__ kn, const ushort_t* __restrict__ kr,
               const ushort_t* __restrict__ vt, ushort_t* __restrict__ out) {
  __shared__ __align__(16) ushort_t Ks[2][8192];   // [64 k][128 d], rows 256B, swizzled
  __shared__ __align__(16) ushort_t Vts[2][8192];  // [128 d][64 s], rows 128B, swizzled
  __shared__ __align__(16) ushort_t Ps[8192];      // per-wave [16 q][64 k], swizzled
  const int tid = threadIdx.x, lane = tid & 63, wid = tid >> 6;
  const int g = lane >> 4, lq = lane & 15;
  const int bh = blockIdx.x, b = bh >> 4, h = bh & 15;
  const float scale = 0.08838834764831845f;  // 1/sqrt(128)
  char* Pbase = (char*)Ps + wid * 2048;

  // stage: 16 K-chunks + 16 Vt-chunks over 8 waves -> 2+2 per wave
  auto stage = [&](int bsel, int kt) {
    const int k0s = kt * 64;
#pragma unroll
    for (int i = 0; i < 2; ++i) {
      const int cc = wid * 2 + i;
      const int o = cc * 1024 + lane * 16;
      {
        const int row = o >> 8;
        const int dK = ((o & 255) ^ ((row & 7) << 4)) >> 1;
        const long krow = (long)b * 2048 + k0s + row;
        const ushort_t* srcK = (dK < 64) ? (kn + krow * 1024 + h * 64 + dK)
                                         : (kr + krow * 1024 + h * 64 + (dK - 64));
        __builtin_amdgcn_global_load_lds((const __attribute__((address_space(1))) unsigned int*)srcK,
            (__attribute__((address_space(3))) unsigned int*)((char*)Ks[bsel] + cc * 1024), 16, 0, 0);
      }
      {
        const int dr = o >> 7;
        const int se = ((o & 127) ^ ((dr & 7) << 4)) >> 1;
        const ushort_t* srcV = vt + ((long)bh * 128 + dr) * 2048 + k0s + se;
        __builtin_amdgcn_global_load_lds((const __attribute__((address_space(1))) unsigned int*)srcV,
            (__attribute__((address_space(3))) unsigned int*)((char*)Vts[bsel] + cc * 1024), 16, 0, 0);
      }
    }
  };

  const int pair = blockIdx.y;
  for (int half = 0; half < 2; ++half) {
    const int t = half ? (15 - pair) : pair;
    const int q0 = t * 128;
    const int qw0 = q0 + wid * 16;
    short8 aq[4];
    {
      const long grow = (long)b * 2048 + qw0 + lq;
#pragma unroll
      for (int ks = 0; ks < 4; ++ks) {
        const int d = ks * 32 + g * 8;
        const ushort_t* src = (d < 64) ? (qn + grow * 1024 + h * 64 + d)
                                       : (qrs + grow * 64 + (d - 64));
        aq[ks] = *(const short8*)src;
      }
    }
    f32x4 oacc[8];
#pragma unroll
    for (int n = 0; n < 8; ++n) oacc[n] = (f32x4){0.f, 0.f, 0.f, 0.f};
    float sm[4] = {-3e38f, -3e38f, -3e38f, -3e38f};
    float sl[4] = {0.f, 0.f, 0.f, 0.f};

    const int kmax = 2 * t + 2;  // k-tiles covering [0, (t+1)*128)
    int cur = 0;
    stage(0, 0);
    for (int kt = 0; kt < kmax; ++kt) {
      const int k0 = kt * 64;
      if (kt < kmax - 1) {
        stage(cur ^ 1, kt + 1);
        asm volatile("s_waitcnt vmcnt(4)" ::: "memory");  // cur tile's 4 done; next's in flight
      } else {
        asm volatile("s_waitcnt vmcnt(0)" ::: "memory");
      }
      __builtin_amdgcn_s_barrier();
      __builtin_amdgcn_sched_barrier(0);

      // ---- QK^T: S[16q][64k] (raw; scale folded into exp) ----
      f32x4 sacc[4];
#pragma unroll
      for (int n = 0; n < 4; ++n) sacc[n] = (f32x4){0.f, 0.f, 0.f, 0.f};
      __builtin_amdgcn_s_setprio(1);
#pragma unroll
      for (int ks = 0; ks < 4; ++ks) {
        const int x = ks * 64 + g * 16;
#pragma unroll
        for (int n = 0; n < 4; ++n) {
          const int kl = n * 16 + lq;
          short8 bk = *(const short8*)((const char*)Ks[cur] + kl * 256 + (x ^ ((kl & 7) << 4)));
          sacc[n] = __builtin_amdgcn_mfma_f32_16x16x32_bf16(aq[ks], bk, sacc[n], 0, 0, 0);
        }
      }
      __builtin_amdgcn_s_setprio(0);
      if (k0 + 63 > qw0) {  // diagonal region for this wave: causal mask
#pragma unroll
        for (int n = 0; n < 4; ++n) {
          const int key = k0 + n * 16 + lq;
#pragma unroll
          for (int j = 0; j < 4; ++j) {
            const int qrow = qw0 + g * 4 + j;
            if (key > qrow) sacc[n][j] = -3e38f;
          }
        }
      }
      // ---- online softmax with defer-max ----
      float tmax[4];
#pragma unroll
      for (int j = 0; j < 4; ++j)
        tmax[j] = fmaxf(fmaxf(sacc[0][j], sacc[1][j]), fmaxf(sacc[2][j], sacc[3][j]));
#pragma unroll
      for (int off = 1; off < 16; off <<= 1)
#pragma unroll
        for (int j = 0; j < 4; ++j) tmax[j] = fmaxf(tmax[j], __shfl_xor(tmax[j], off));
      bool need = false;
#pragma unroll
      for (int j = 0; j < 4; ++j) {
        tmax[j] *= scale;
        need = need || (tmax[j] > sm[j] + 8.f);
      }
      if (__any(need)) {
#pragma unroll
        for (int j = 0; j < 4; ++j) {
          const float mn = fmaxf(sm[j], tmax[j]);
          const float fr = __expf(sm[j] - mn);
          sm[j] = mn;
          sl[j] *= fr;
#pragma unroll
          for (int n = 0; n < 8; ++n) oacc[n][j] *= fr;
        }
      }
      f32x4 p[4];
#pragma unroll
      for (int n = 0; n < 4; ++n)
#pragma unroll
        for (int j = 0; j < 4; ++j)
          p[n][j] = __expf(__builtin_fmaf(sacc[n][j], scale, -sm[j]));
      float psum[4];
#pragma unroll
      for (int j = 0; j < 4; ++j) psum[j] = p[0][j] + p[1][j] + p[2][j] + p[3][j];
#pragma unroll
      for (int off = 1; off < 16; off <<= 1)
#pragma unroll
        for (int j = 0; j < 4; ++j) psum[j] += __shfl_xor(psum[j], off);
#pragma unroll
      for (int j = 0; j < 4; ++j) sl[j] += psum[j];
      // ---- P -> LDS (bf16, swizzled; per-wave region) ----
#pragma unroll
      for (int n = 0; n < 4; ++n) {
        const int col2 = (n * 16 + lq) * 2;
#pragma unroll
        for (int j = 0; j < 4; ++j) {
          const int row = g * 4 + j;
          *(ushort_t*)(Pbase + row * 128 + (col2 ^ ((row & 7) << 4))) = f2bf(p[n][j]);
        }
      }
      // ---- PV: O[16q][128d] += P[16q][64k] * Vt[128d][64k]^T ----
      __builtin_amdgcn_s_setprio(1);
#pragma unroll
      for (int ks2 = 0; ks2 < 2; ++ks2) {
        const int x = ks2 * 64 + g * 16;
        short8 pa = *(const short8*)(Pbase + lq * 128 + (x ^ ((lq & 7) << 4)));
#pragma unroll
        for (int nd = 0; nd < 8; ++nd) {
          const int dl = nd * 16 + lq;
          short8 vb = *(const short8*)((const char*)Vts[cur] + dl * 128 + (x ^ ((dl & 7) << 4)));
          oacc[nd] = __builtin_amdgcn_mfma_f32_16x16x32_bf16(pa, vb, oacc[nd], 0, 0, 0);
        }
      }
      __builtin_amdgcn_s_setprio(0);
      __builtin_amdgcn_sched_barrier(0);
      __builtin_amdgcn_s_barrier();
      cur ^= 1;
    }
    // ---- epilogue ----
    float inv[4];
#pragma unroll
    for (int j = 0; j < 4; ++j) inv[j] = 1.f / sl[j];
#pragma unroll
    for (int nd = 0; nd < 8; ++nd) {
      const int d = nd * 16 + lq;
#pragma unroll
      for (int j = 0; j < 4; ++j) {
        const long row = (long)b * 2048 + qw0 + g * 4 + j;
        out[row * 2048 + h * 128 + d] = f2bf(oacc[nd][j] * inv[j]);
      }
    }
  }
}

// ---------------- launch ----------------
// Workspace: EXACTLY 101,711,872 B (round-3-proven bound).
// kraw_bf relocated to QNOPE region (76546048): written by merged xproj,
// consumed by rope_kraw BEFORE qproj overwrites it with qnope.
extern "C" void kernel_launch(void* const* d_in, const int* in_sizes, int n_in,
                              void* d_out, int out_size, void* d_ws, size_t ws_size,
                              hipStream_t stream) {
  const float* x      = (const float*)d_in[0];
  const float* fcos   = (const float*)d_in[1];
  const float* fsin   = (const float*)d_in[2];
  const float* w_cq   = (const float*)d_in[3];
  const float* w_dqn  = (const float*)d_in[4];
  const float* w_dqr  = (const float*)d_in[5];
  const float* w_ckv  = (const float*)d_in[6];
  const float* w_dkn  = (const float*)d_in[7];
  const float* w_dv   = (const float*)d_in[8];
  const float* w_kr   = (const float*)d_in[9];
  const float* w_proj = (const float*)d_in[10];
  const float* qnw    = (const float*)d_in[11];
  const float* kvnw   = (const float*)d_in[12];
  float* out = (float*)d_out;

  char* ws = (char*)d_ws;
  ushort_t* x_bf     = (ushort_t*)(ws + 0);
  ushort_t* wcq_bf   = (ushort_t*)(ws + 16777216);
  ushort_t* wdqn_bf  = (ushort_t*)(ws + 23068672);
  ushort_t* wdqr_bf  = (ushort_t*)(ws + 26214400);
  ushort_t* wckv_bf  = (ushort_t*)(ws + 29360128);
  ushort_t* wdkn_bf  = (ushort_t*)(ws + 31457280);
  ushort_t* wdv_bf   = (ushort_t*)(ws + 32505856);
  ushort_t* wpr_bf   = (ushort_t*)(ws + 34603008);
  ushort_t* cq_bf    = (ushort_t*)(ws + 42991616);  // CQ region [43.0M,55.57M)
  ushort_t* krope_bf = (ushort_t*)(ws + 42991616);  //   after cq dead (tv_rope)
  ushort_t* qrs_bf   = (ushort_t*)(ws + 51904512);  //   after cq dead (rope_kraw)
  ushort_t* ckv_bf   = (ushort_t*)(ws + 55574528);  // CKVNQ region
  ushort_t* nq_bf    = (ushort_t*)(ws + 59768832);
  ushort_t* attn_bf  = (ushort_t*)(ws + 55574528);  //   after ckv/nq dead
  ushort_t* nkv_bf   = (ushort_t*)(ws + 72351744);
  ushort_t* qnope_bf = (ushort_t*)(ws + 76546048);  // QNOPE region
  ushort_t* kraw_bf  = (ushort_t*)(ws + 76546048);  //   before qnope written
  ushort_t* qr_bf    = (ushort_t*)(ws + 0);         // X region, after x_bf dead
  ushort_t* knope_bf = (ushort_t*)(ws + 8388608);
  ushort_t* v_bf     = (ushort_t*)(ws + 84934656);  // V region
  ushort_t* wkr_bf   = (ushort_t*)(ws + 84934656);  //   before v_bf written
  ushort_t* vt_bf    = (ushort_t*)(ws + 16777216);  // dead weight region

  // 1. all converts
  cvt_all<<<21120, 256, 0, stream>>>(x, w_cq, w_dqn, w_dqr, w_ckv, w_dkn, w_dv, w_kr, w_proj,
                                     x_bf, wcq_bf, wdqn_bf, wdqr_bf, wckv_bf, wdkn_bf,
                                     wdv_bf, wkr_bf, wpr_bf);
  // 2. merged x-projections: [ckv 4 | cq 12 | kraw 1] blocks, K=2048 (x_bf, wkr dead after)
  gemm_bt3<<<dim3(17, 32), 256, 0, stream>>>(x_bf,
                                             wckv_bf, ckv_bf, 4, 512,
                                             wcq_bf, cq_bf, 12, 1536,
                                             wkr_bf, kraw_bf, 64, 2048);
  // 3. both rmsnorms (ckv, cq dead after)
  rmsnorm_both<<<8192, 256, 0, stream>>>(ckv_bf, kvnw, nkv_bf, cq_bf, qnw, nq_bf);
  // 4. rope kraw -> qrs (kraw dead after; cq dead so CQ-region write is safe)
  rope_kraw<<<512, 256, 0, stream>>>(kraw_bf, qrs_bf, fcos, fsin);
  // 5. merged q-projections: [qnope 8 | qr 8], K=1536 (nq dead after; qnope overwrites dead kraw)
  gemm_bt3<<<dim3(16, 32), 256, 0, stream>>>(nq_bf,
                                             wdqn_bf, qnope_bf, 8, 1024,
                                             wdqr_bf, qr_bf, 8, 1024,
                                             wdqn_bf, qnope_bf, 1024, 1536);
  // 6. merged kv-projections: [knope 8 | v 16], K=512 (nkv dead after)
  gemm_bt3<<<dim3(24, 32), 256, 0, stream>>>(nkv_bf,
                                             wdkn_bf, knope_bf, 8, 1024,
                                             wdv_bf, v_bf, 16, 2048,
                                             wdkn_bf, knope_bf, 1024, 512);
  // 7. transpose_v + rope qr->krope (weights wcq..wdv dead; vt into that region)
  tv_rope<<<9216, 256, 0, stream>>>(v_bf, vt_bf, qr_bf, krope_bf, fcos, fsin);
  // 8. MFMA flash attention v4 (8-wave blocks, 128-row q-tiles, pairs of 16 tiles)
  attn_mfma<<<dim3(32, 8), 512, 0, stream>>>(qnope_bf, qrs_bf, knope_bf, krope_bf, vt_bf, attn_bf);
  // 9. final projection (fp32 out)
  gemm_bt<0><<<dim3(16, 32), 256, 0, stream>>>(attn_bf, wpr_bf, out, 4096, 2048, 2048);
}